// Round 5
// baseline (756.640 us; speedup 1.0000x reference)
//
#include <hip/hip_runtime.h>

// Problem constants
#define B_    64
#define C_    256
#define H_    32
#define W_    32
#define K_    1024
#define D_    256
#define HW_   1024
#define N_    65536
#define NELEM 16777216
#define DECAY_ 0.99f
#define OMD_   0.01f
#define EPS_   1e-5f
#define TAU_   0.05f        // fp64-rescan margin

// d_out float offsets
#define OFF_LOSS    16777216
#define OFF_ENT     16777217
#define OFF_ENC     16777218   // 8B-aligned only
#define OFF_CLUSTER 83886082
#define OFF_NEWW    83887106
#define OFF_NEWEMB  84149250

// Scratch inside the (later overwritten) encodings output region [OFF_ENC, OFF_ENC+67108864):
#define OFF_XHI     (OFF_ENC + 2)              // 16B-aligned; bf16 hi of -2x, [N][D] ushort
#define OFF_XLO     (OFF_XHI + 8388608)
#define OFF_EHI     (OFF_XLO + 8388608)        // bf16 hi of emb, PACKED B-fragment layout (see k_prep_e)
#define OFF_ELO     (OFF_EHI + 131072)
#define OFF_SORT2   (OFF_ELO + 131072)         // sorted[65536] | offsets[1025] | cursor[1024]
// Scratch ends at rel 17106947 (floats rel. to OFF_ENC). First 16B-aligned abs index after:
#define ZTAIL_ABS   33884168                   // = OFF_ENC + 17106950, abs%4==0
#define ZTAIL_F4    12500478                   // float4s in [rel 17106950, rel 67108862)
#define ZHEAD_F4    4276737                    // float4s in [rel 2, rel 17106950)

typedef __attribute__((ext_vector_type(8)))  short short8;
typedef __attribute__((ext_vector_type(16))) float floatx16;

__device__ __forceinline__ unsigned short f2bf(float f) {
    unsigned u = __float_as_uint(f);
    return (unsigned short)((u + 0x7fffu + ((u >> 16) & 1u)) >> 16);
}
__device__ __forceinline__ float bf2f(unsigned short h) {
    return __uint_as_float(((unsigned)h) << 16);
}

__global__ __launch_bounds__(256) void k_zero(float* __restrict__ dw, int* __restrict__ small_) {
    int g = blockIdx.x * 256 + threadIdx.x;
    dw[g] = 0.0f;                  // grid 1024*256 == 262144 == K*D exactly
    if (g < 1026) small_[g] = 0;   // counts[1024] + flagcount + losssum
}

// emb -> bf16 hi/lo + enorm.
// PACKED layout for MFMA B-fragments: tile = [K/32][ds=16][h=2][c32=32][j=8] ushorts,
// so a wave's load for a fixed (ds,h) is one contiguous 1KB transaction, and a
// whole 16KB tile is contiguous for global_load_lds staging.
// Element (k, d) lands at: tile(k>>5), ds=d>>4, h=(d>>3)&1, c32=k&31, j=d&7.
__global__ __launch_bounds__(64) void k_prep_e(const float* __restrict__ emb,
                                               unsigned short* __restrict__ ehi,
                                               unsigned short* __restrict__ elo,
                                               float* __restrict__ enorm) {
    const int k = blockIdx.x;
    const int t = threadIdx.x;       // handles d = 4t .. 4t+3 (same ds, same h)
    float4 v = ((const float4*)(emb + (size_t)k * D_))[t];
    float s = v.x * v.x + v.y * v.y + v.z * v.z + v.w * v.w;
    ushort4 hi, lo;
    {
        float f[4] = {v.x, v.y, v.z, v.w};
        unsigned short h[4], l[4];
        #pragma unroll
        for (int j = 0; j < 4; ++j) {
            h[j] = f2bf(f[j]);
            l[j] = f2bf(f[j] - bf2f(h[j]));
        }
        hi = make_ushort4(h[0], h[1], h[2], h[3]);
        lo = make_ushort4(l[0], l[1], l[2], l[3]);
    }
    // packed offset in ushorts:
    // (k>>5)*8192 + (t>>2)*512 + ((t>>1)&1)*256 + (k&31)*8 + (t&1)*4
    size_t o = ((size_t)(k >> 5) << 13) + ((size_t)(t >> 2) << 9)
             + (((size_t)(t >> 1) & 1) << 8) + ((size_t)(k & 31) << 3) + ((t & 1) << 2);
    *(ushort4*)(ehi + o) = hi;
    *(ushort4*)(elo + o) = lo;
    #pragma unroll
    for (int off = 32; off > 0; off >>= 1) s += __shfl_down(s, off);
    if (t == 0) enorm[k] = s;
}

// NCHW -> n-major bf16 hi/lo split of (-2x). Tile 32 d x 256 n per block.
__global__ __launch_bounds__(256) void k_prep_x(const float* __restrict__ inp,
                                                unsigned short* __restrict__ xhi,
                                                unsigned short* __restrict__ xlo) {
    __shared__ float tile[32][257];
    const int tid = threadIdx.x;
    const int bid = blockIdx.x;            // 2048 blocks: b(64) x hwtile(4) x dtile(8)
    const int dt = bid & 7;
    const int ht = (bid >> 3) & 3;
    const int b = bid >> 5;
    const int d0 = dt * 32;
    const int hw0 = ht * 256;
    const float* src = inp + (size_t)b * (C_ * HW_) + (size_t)d0 * HW_ + hw0;
    #pragma unroll
    for (int i = 0; i < 8; ++i) {
        int idx4 = i * 256 + tid;
        int dl = idx4 >> 6;
        int nl4 = (idx4 & 63) * 4;
        float4 v = *(const float4*)(src + (size_t)dl * HW_ + nl4);
        tile[dl][nl4] = v.x; tile[dl][nl4 + 1] = v.y;
        tile[dl][nl4 + 2] = v.z; tile[dl][nl4 + 3] = v.w;
    }
    __syncthreads();
    const int nbase = b * HW_ + hw0;
    #pragma unroll
    for (int i = 0; i < 4; ++i) {
        int f8 = i * 256 + tid;            // 1024 items of 8 d
        int nl = f8 >> 2;
        int dpos = (f8 & 3) * 8;
        union { unsigned short u[8]; short8 v; } ph, pl;
        #pragma unroll
        for (int j = 0; j < 8; ++j) {
            float f = -2.0f * tile[dpos + j][nl];
            unsigned short h = f2bf(f);
            ph.u[j] = h;
            pl.u[j] = f2bf(f - bf2f(h));
        }
        size_t o = (size_t)(nbase + nl) * D_ + d0 + dpos;
        *(short8*)(xhi + o) = ph.v;
        *(short8*)(xlo + o) = pl.v;
    }
}

// Stage one 16KB+16KB packed B tile into LDS via direct global->LDS DMA.
// 128 threads: 8 iters x 2 arrays = exactly 16 gload_lds instructions per thread.
__device__ __forceinline__ void stage_tile(const unsigned short* __restrict__ gh,
                                           const unsigned short* __restrict__ gl,
                                           unsigned short* sh, unsigned short* sl,
                                           int tid) {
    #pragma unroll
    for (int i = 0; i < 8; ++i) {
        __builtin_amdgcn_global_load_lds(
            (const __attribute__((address_space(1))) unsigned int*)(gh + i * 1024 + tid * 8),
            (__attribute__((address_space(3))) unsigned int*)(sh + i * 1024 + tid * 8),
            16, 0, 0);
        __builtin_amdgcn_global_load_lds(
            (const __attribute__((address_space(1))) unsigned int*)(gl + i * 1024 + tid * 8),
            (__attribute__((address_space(3))) unsigned int*)(sl + i * 1024 + tid * 8),
            16, 0, 0);
    }
}

// MFMA bf16x3 distance argmin, 64 ROWS PER WAVE (2 row-tiles, 4 indep acc chains).
// 128-thread blocks, grid 512 -> 4 waves/CU at ~450 VGPR (1 wave/SIMD).
// Rationale: LDS read BW (85 B/cyc) was the co-bottleneck at 8 waves/CU x 32KB/step;
// halving wave count halves LDS reads per B-tile byte.
// Barrier is counted-vmcnt (T4): per step each wave issues EXACTLY 16 gload_lds then
// EXACTLY 6 zero-fill stores (index-clamped, zeros are idempotent), so
// s_waitcnt vmcnt(6) = "all gloads done, stores still in flight across the barrier".
__global__ __launch_bounds__(128, 1) void k_argmin(
    const unsigned short* __restrict__ xhi, const unsigned short* __restrict__ xlo,
    const unsigned short* __restrict__ ehi, const unsigned short* __restrict__ elo,
    const float* __restrict__ enorm, int* __restrict__ idx_out,
    int* __restrict__ flagcount, int* __restrict__ flaglist,
    float4* __restrict__ encz)
{
    __shared__ unsigned short smem[2][2][8192];   // [buf][hi/lo][16KB] = 64KB
    const int tid = threadIdx.x;
    const int w = tid >> 6;                       // 0..1
    const int lane = tid & 63;
    const int c32 = lane & 31;
    const int h = lane >> 5;
    const int r0 = blockIdx.x * 128 + w * 64;     // 64 rows per wave
    const int gtid = blockIdx.x * 128 + tid;      // 0..65535
    const float4 z4 = make_float4(0.f, 0.f, 0.f, 0.f);

    // A fragments for 2 row-tiles: row m = lane&31, k = h*8 + j within each 16-chunk
    short8 Ahi[2][16], Alo[2][16];
    #pragma unroll
    for (int rt = 0; rt < 2; ++rt) {
        const unsigned short* pa = xhi + (size_t)(r0 + rt * 32 + c32) * D_ + h * 8;
        const unsigned short* pl = xlo + (size_t)(r0 + rt * 32 + c32) * D_ + h * 8;
        #pragma unroll
        for (int ds = 0; ds < 16; ++ds) {
            Ahi[rt][ds] = *(const short8*)(pa + ds * 16);
            Alo[rt][ds] = *(const short8*)(pl + ds * 16);
        }
    }

    float b1[2][16], b2[2][16];
    int bi[2][16];
    #pragma unroll
    for (int rt = 0; rt < 2; ++rt)
        #pragma unroll
        for (int i = 0; i < 16; ++i) { b1[rt][i] = 3.0e38f; b2[rt][i] = 3.0e38f; bi[rt][i] = 0; }

    // prologue: stage tile 0 into buffer 0 (full drain barrier is fine here)
    stage_tile(ehi, elo, &smem[0][0][0], &smem[0][1][0], tid);
    __syncthreads();

    // per-lane read base within a staged tile: h*256 + c32*8 ushorts
    const int rb = (h << 8) + (c32 << 3);

    int cb = 0;
    for (int ct = 0; ct < 32; ++ct) {
        if (ct + 1 < 32) {
            stage_tile(ehi + (size_t)(ct + 1) * 8192, elo + (size_t)(ct + 1) * 8192,
                       &smem[cb ^ 1][0][0], &smem[cb ^ 1][1][0], tid);
        }
        // background zero-fill of the encodings tail: EXACTLY 6 stores, clamped
        // (duplicate zero writes are harmless; keeps vmcnt bookkeeping exact)
        #pragma unroll
        for (int jj = 0; jj < 6; ++jj) {
            int zi = (ct * 6 + jj) * 65536 + gtid;
            zi = (zi < ZTAIL_F4) ? zi : (ZTAIL_F4 - 1);
            encz[zi] = z4;
        }
        const int col = ct * 32 + c32;
        const float en = enorm[col];
        const unsigned short* sbh = &smem[cb][0][rb];
        const unsigned short* sbl = &smem[cb][1][rb];
        floatx16 hh0, cr0, hh1, cr1;
        #pragma unroll
        for (int i = 0; i < 16; ++i) { hh0[i] = 0.0f; cr0[i] = 0.0f; hh1[i] = 0.0f; cr1[i] = 0.0f; }
        #pragma unroll
        for (int ds = 0; ds < 16; ++ds) {
            short8 bh = *(const short8*)(sbh + ds * 512);
            short8 bl = *(const short8*)(sbl + ds * 512);
            hh0 = __builtin_amdgcn_mfma_f32_32x32x16_bf16(Ahi[0][ds], bh, hh0, 0, 0, 0);
            cr0 = __builtin_amdgcn_mfma_f32_32x32x16_bf16(Ahi[0][ds], bl, cr0, 0, 0, 0);
            hh1 = __builtin_amdgcn_mfma_f32_32x32x16_bf16(Ahi[1][ds], bh, hh1, 0, 0, 0);
            cr1 = __builtin_amdgcn_mfma_f32_32x32x16_bf16(Ahi[1][ds], bl, cr1, 0, 0, 0);
            cr0 = __builtin_amdgcn_mfma_f32_32x32x16_bf16(Alo[0][ds], bh, cr0, 0, 0, 0);
            cr1 = __builtin_amdgcn_mfma_f32_32x32x16_bf16(Alo[1][ds], bh, cr1, 0, 0, 0);
        }
        #pragma unroll
        for (int r = 0; r < 16; ++r) {
            {
                float v = hh0[r] + cr0[r] + en;
                bool lt = v < b1[0][r];
                float nb2 = lt ? b1[0][r] : fminf(v, b2[0][r]);
                b2[0][r] = nb2;
                b1[0][r] = lt ? v : b1[0][r];
                bi[0][r] = lt ? col : bi[0][r];
            }
            {
                float v = hh1[r] + cr1[r] + en;
                bool lt = v < b1[1][r];
                float nb2 = lt ? b1[1][r] : fminf(v, b2[1][r]);
                b2[1][r] = nb2;
                b1[1][r] = lt ? v : b1[1][r];
                bi[1][r] = lt ? col : bi[1][r];
            }
        }
        // counted-vmcnt barrier: all 16 gloads of the ct+1 stage are complete,
        // the 6 newest zero-stores may remain in flight.
        asm volatile("s_waitcnt vmcnt(6)" ::: "memory");
        __builtin_amdgcn_sched_barrier(0);
        __builtin_amdgcn_s_barrier();
        __builtin_amdgcn_sched_barrier(0);
        cb ^= 1;
    }

    // reduce each reg's (b1,b2,bi) across the 32 lanes sharing that row
    #pragma unroll
    for (int rt = 0; rt < 2; ++rt) {
        #pragma unroll
        for (int r = 0; r < 16; ++r) {
            float B1 = b1[rt][r], B2 = b2[rt][r];
            int Bi = bi[rt][r];
            #pragma unroll
            for (int mask = 1; mask <= 16; mask <<= 1) {
                float v1 = __shfl_xor(B1, mask);
                float v2 = __shfl_xor(B2, mask);
                int i1 = __shfl_xor(Bi, mask);
                if (v1 < B1 || (v1 == B1 && i1 < Bi)) {
                    B2 = fminf(fminf(B1, B2), v2);
                    B1 = v1; Bi = i1;
                } else {
                    B2 = fminf(B2, fminf(v1, v2));
                }
            }
            if (c32 == 0) {
                int row = r0 + rt * 32 + (r & 3) + 4 * h + 8 * (r >> 2);
                idx_out[row] = Bi;
                if (B2 - B1 < TAU_) {
                    int p = atomicAdd(flagcount, 1);
                    flaglist[p] = row;
                }
            }
        }
    }
}

// Exact fp64 rescan of flagged (near-tie) rows.
__global__ __launch_bounds__(256) void k_rescan(
    const float* __restrict__ inp, const float* __restrict__ emb,
    const int* __restrict__ flagcount, const int* __restrict__ flaglist,
    int* __restrict__ idx_out)
{
    __shared__ double xd[256];
    __shared__ double sv[256];
    __shared__ int si[256];
    const int tid = threadIdx.x;
    const int nflag = *flagcount;
    for (int f = blockIdx.x; f < nflag; f += gridDim.x) {
        int n = flaglist[f];
        int b = n >> 10, nn = n & 1023;
        xd[tid] = (double)inp[(size_t)b * (C_ * HW_) + (size_t)tid * HW_ + nn];
        __syncthreads();
        double bv = 1e300; int bi = 0;
        for (int k = tid; k < K_; k += 256) {
            const float* ep = emb + (size_t)k * D_;
            double dot = 0.0, en = 0.0;
            for (int d = 0; d < D_; ++d) {
                double e = (double)ep[d];
                dot = fma(xd[d], e, dot);
                en  = fma(e, e, en);
            }
            double v = en - 2.0 * dot;
            if (v < bv) { bv = v; bi = k; }
        }
        sv[tid] = bv; si[tid] = bi;
        __syncthreads();
        for (int s = 128; s > 0; s >>= 1) {
            if (tid < s) {
                if (sv[tid + s] < sv[tid] || (sv[tid + s] == sv[tid] && si[tid + s] < si[tid])) {
                    sv[tid] = sv[tid + s]; si[tid] = si[tid + s];
                }
            }
            __syncthreads();
        }
        if (tid == 0) idx_out[n] = si[0];
        __syncthreads();
    }
}

__global__ __launch_bounds__(256) void k_hist(const int* __restrict__ idx, int* __restrict__ counts) {
    __shared__ int h[1024];
    const int tid = threadIdx.x;
    #pragma unroll
    for (int j = 0; j < 4; ++j) h[tid + j * 256] = 0;
    __syncthreads();
    #pragma unroll
    for (int j = 0; j < 4; ++j) {
        int n = blockIdx.x * 1024 + j * 256 + tid;
        atomicAdd(&h[idx[n]], 1);
    }
    __syncthreads();
    #pragma unroll
    for (int j = 0; j < 4; ++j) {
        int v = h[tid + j * 256];
        if (v) atomicAdd(&counts[tid + j * 256], v);
    }
}

__global__ __launch_bounds__(1024) void k_scan(const int* __restrict__ counts,
                                               int* __restrict__ offsets, int* __restrict__ cursor) {
    __shared__ int s[1024];
    const int t = threadIdx.x;
    const int c = counts[t];
    s[t] = c;
    __syncthreads();
    for (int off = 1; off < 1024; off <<= 1) {
        int v = (t >= off) ? s[t - off] : 0;
        __syncthreads();
        s[t] += v;
        __syncthreads();
    }
    int excl = s[t] - c;
    offsets[t] = excl;
    cursor[t] = excl;
    if (t == 1023) offsets[1024] = s[1023];
}

// Block-aggregated scatter.
__global__ __launch_bounds__(256) void k_scatter(const int* __restrict__ idx,
                                                 int* __restrict__ cursor, int* __restrict__ sorted) {
    __shared__ int hc[1024];
    __shared__ int hb[1024];
    const int tid = threadIdx.x;
    const int base = blockIdx.x * 1024;
    #pragma unroll
    for (int j = 0; j < 4; ++j) hc[tid + j * 256] = 0;
    __syncthreads();
    int myk[4], myn[4];
    #pragma unroll
    for (int j = 0; j < 4; ++j) {
        int n = base + j * 256 + tid;
        myn[j] = n;
        myk[j] = idx[n];
        atomicAdd(&hc[myk[j]], 1);
    }
    __syncthreads();
    #pragma unroll
    for (int j = 0; j < 4; ++j) {
        int kk = tid + j * 256;
        int c = hc[kk];
        hb[kk] = c ? atomicAdd(&cursor[kk], c) : 0;
    }
    __syncthreads();
    #pragma unroll
    for (int j = 0; j < 4; ++j) hc[tid + j * 256] = 0;
    __syncthreads();
    #pragma unroll
    for (int j = 0; j < 4; ++j) {
        int p = hb[myk[j]] + atomicAdd(&hc[myk[j]], 1);
        sorted[p] = myn[j];
    }
}

// Balanced segmented dw reduction reading xhi/xlo (x = -0.5*(hi+lo), exact to 2^-18).
__global__ __launch_bounds__(256) void k_dwg(const unsigned short* __restrict__ xhi,
                                             const unsigned short* __restrict__ xlo,
                                             const int* __restrict__ sorted,
                                             const int* __restrict__ idx,
                                             const int* __restrict__ offsets,
                                             float* __restrict__ dw) {
    const int lane = threadIdx.x & 63;
    const int wid = threadIdx.x >> 6;
    const int wbase = (blockIdx.x * 4 + wid) * 64;

    int myn = sorted[wbase + lane];
    int myk = idx[myn];

    float4 acc = make_float4(0.f, 0.f, 0.f, 0.f);
    int cur = __shfl(myk, 0);

    #pragma unroll 8
    for (int i = 0; i < 64; ++i) {
        int n = __shfl(myn, i);
        int k = __shfl(myk, i);
        if (k != cur) {
            bool full = (offsets[cur] >= wbase) && (offsets[cur + 1] <= wbase + 64);
            float* dwk = dw + (size_t)cur * D_ + lane * 4;
            if (full) {
                ((float2*)dwk)[0] = make_float2(-0.5f * acc.x, -0.5f * acc.y);
                ((float2*)dwk)[1] = make_float2(-0.5f * acc.z, -0.5f * acc.w);
            } else {
                atomicAdd(dwk + 0, -0.5f * acc.x);
                atomicAdd(dwk + 1, -0.5f * acc.y);
                atomicAdd(dwk + 2, -0.5f * acc.z);
                atomicAdd(dwk + 3, -0.5f * acc.w);
            }
            acc = make_float4(0.f, 0.f, 0.f, 0.f);
            cur = k;
        }
        size_t o = (size_t)n * D_ + lane * 4;
        ushort4 hx = *(const ushort4*)(xhi + o);
        ushort4 lx = *(const ushort4*)(xlo + o);
        acc.x += bf2f(hx.x) + bf2f(lx.x);
        acc.y += bf2f(hx.y) + bf2f(lx.y);
        acc.z += bf2f(hx.z) + bf2f(lx.z);
        acc.w += bf2f(hx.w) + bf2f(lx.w);
    }
    {
        bool full = (offsets[cur] >= wbase) && (offsets[cur + 1] <= wbase + 64);
        float* dwk = dw + (size_t)cur * D_ + lane * 4;
        if (full) {
            ((float2*)dwk)[0] = make_float2(-0.5f * acc.x, -0.5f * acc.y);
            ((float2*)dwk)[1] = make_float2(-0.5f * acc.z, -0.5f * acc.w);
        } else {
            atomicAdd(dwk + 0, -0.5f * acc.x);
            atomicAdd(dwk + 1, -0.5f * acc.y);
            atomicAdd(dwk + 2, -0.5f * acc.z);
            atomicAdd(dwk + 3, -0.5f * acc.w);
        }
    }
}

// Zero only the scratch-occupied head of encodings (the 200MB tail was zeroed
// inside k_argmin). Region [OFF_ENC+2, OFF_ENC+17106950) as float4 + head/tail scalars.
__global__ __launch_bounds__(256) void k_enc0(float* __restrict__ enc) {
    const float4 z = make_float4(0.f, 0.f, 0.f, 0.f);
    float4* p = (float4*)(enc + 2);
    int t = blockIdx.x * 256 + threadIdx.x;     // 4096*256 = 1048576 threads
    #pragma unroll
    for (int it = 0; it < 5; ++it) {
        int i = it * 1048576 + t;
        if (i < ZHEAD_F4) p[i] = z;
    }
    if (t == 0) { enc[0] = 0.f; enc[1] = 0.f; enc[67108862] = 0.f; enc[67108863] = 0.f; }
}

__global__ __launch_bounds__(256) void k_enc1(const int* __restrict__ idx, float* __restrict__ enc) {
    #pragma unroll
    for (int j = 0; j < 4; ++j) {
        int n = blockIdx.x * 1024 + j * 256 + threadIdx.x;
        enc[(size_t)n * 1024 + idx[n]] = 1.0f;
    }
}

__global__ __launch_bounds__(256) void k_quant(
    const float* __restrict__ inp, const float* __restrict__ emb,
    const int* __restrict__ idx, float* __restrict__ outp, float* __restrict__ losssum)
{
    __shared__ float red[256];
    const int tid = threadIdx.x;
    float s = 0.0f;
    const int base = blockIdx.x * 1024;
    #pragma unroll
    for (int it = 0; it < 4; ++it) {
        int g = base + it * 256 + tid;
        int o = g << 2;
        int b = o >> 18;
        int c = (o >> 10) & 255;
        int hw = o & 1023;
        int n = (b << 10) + hw;
        float4 x = ((const float4*)inp)[g];
        int4 ki = *(const int4*)(idx + n);
        float q0 = emb[(size_t)ki.x * D_ + c];
        float q1 = emb[(size_t)ki.y * D_ + c];
        float q2 = emb[(size_t)ki.z * D_ + c];
        float q3 = emb[(size_t)ki.w * D_ + c];
        float d0 = q0 - x.x, d1 = q1 - x.y, d2 = q2 - x.z, d3 = q3 - x.w;
        ((float4*)outp)[g] = make_float4(x.x + d0, x.y + d1, x.z + d2, x.w + d3);
        s += d0 * d0 + d1 * d1 + d2 * d2 + d3 * d3;
    }
    red[tid] = s;
    __syncthreads();
    for (int t = 128; t > 0; t >>= 1) {
        if (tid < t) red[tid] += red[tid + t];
        __syncthreads();
    }
    if (tid == 0) atomicAdd(losssum, red[0]);
}

__global__ __launch_bounds__(1024) void k_cluster(
    const float* __restrict__ ema_cs, const int* __restrict__ counts,
    const float* __restrict__ losssum, float* __restrict__ out_cluster,
    float* __restrict__ out_loss, float* __restrict__ out_ent)
{
    __shared__ float red[1024];
    const int k = threadIdx.x;
    float cnt = (float)counts[k];
    float raw = ema_cs[k] * DECAY_ + OMD_ * cnt;
    red[k] = raw;
    __syncthreads();
    for (int t = 512; t > 0; t >>= 1) {
        if (k < t) red[k] += red[k + t];
        __syncthreads();
    }
    float nsum = red[0];
    __syncthreads();
    float clv = (raw + EPS_) / (nsum + 1024.0f * EPS_) * nsum;
    out_cluster[k] = clv;
    float p = cnt * (1.0f / 65536.0f);
    red[k] = p * logf(p + 1e-10f);
    __syncthreads();
    for (int t = 512; t > 0; t >>= 1) {
        if (k < t) red[k] += red[k + t];
        __syncthreads();
    }
    if (k == 0) {
        out_ent[0] = -red[0];
        out_loss[0] = 0.25f * losssum[0] * (1.0f / 16777216.0f);
    }
}

__global__ __launch_bounds__(256) void k_fin(
    const float* __restrict__ ema_w, const float* __restrict__ cluster,
    float* __restrict__ neww, float* __restrict__ newemb)
{
    int g = blockIdx.x * 256 + threadIdx.x;
    int k = g >> 8;
    float w = ema_w[g] * DECAY_ + OMD_ * neww[g];   // neww currently holds dw
    neww[g] = w;
    newemb[g] = w / cluster[k];
}

extern "C" void kernel_launch(void* const* d_in, const int* in_sizes, int n_in,
                              void* d_out, int out_size, void* d_ws, size_t ws_size,
                              hipStream_t stream)
{
    const float* inp    = (const float*)d_in[0];
    const float* emb    = (const float*)d_in[1];
    const float* ema_cs = (const float*)d_in[2];
    const float* ema_w  = (const float*)d_in[3];

    float* out0        = (float*)d_out;
    float* out_loss    = out0 + OFF_LOSS;
    float* out_ent     = out0 + OFF_ENT;
    float* out_enc     = out0 + OFF_ENC;
    float* out_cluster = out0 + OFF_CLUSTER;
    float* out_neww    = out0 + OFF_NEWW;
    float* out_newemb  = out0 + OFF_NEWEMB;

    unsigned short* ws_xhi  = (unsigned short*)(out0 + OFF_XHI);
    unsigned short* ws_xlo  = (unsigned short*)(out0 + OFF_XLO);
    unsigned short* ws_ehi  = (unsigned short*)(out0 + OFF_EHI);
    unsigned short* ws_elo  = (unsigned short*)(out0 + OFF_ELO);
    int*   ws_sorted  = (int*)(out0 + OFF_SORT2);
    int*   ws_offsets = ws_sorted + 65536;
    int*   ws_cursor  = ws_offsets + 1025;

    int*   ws_idx    = (int*)d_ws;
    int*   ws_counts = ws_idx + 65536;
    int*   ws_flagc  = ws_idx + 66560;
    float* ws_loss   = (float*)(ws_idx + 66561);
    int*   ws_flagl  = ws_idx + 66562;
    float* ws_enorm  = (float*)(ws_idx + 132098);

    float4* encz = (float4*)(out0 + ZTAIL_ABS);

    k_zero   <<<1024, 256, 0, stream>>>(out_neww, ws_counts);
    k_prep_e <<<1024, 64, 0, stream>>>(emb, ws_ehi, ws_elo, ws_enorm);
    k_prep_x <<<2048, 256, 0, stream>>>(inp, ws_xhi, ws_xlo);
    k_argmin <<<512, 128, 0, stream>>>(ws_xhi, ws_xlo, ws_ehi, ws_elo, ws_enorm,
                                       ws_idx, ws_flagc, ws_flagl, encz);
    k_rescan <<<256, 256, 0, stream>>>(inp, emb, ws_flagc, ws_flagl, ws_idx);
    k_hist   <<<64, 256, 0, stream>>>(ws_idx, ws_counts);
    k_scan   <<<1, 1024, 0, stream>>>(ws_counts, ws_offsets, ws_cursor);
    k_scatter<<<64, 256, 0, stream>>>(ws_idx, ws_cursor, ws_sorted);
    k_dwg    <<<256, 256, 0, stream>>>(ws_xhi, ws_xlo, ws_sorted, ws_idx, ws_offsets, out_neww);
    k_enc0   <<<4096, 256, 0, stream>>>(out_enc);
    k_enc1   <<<64, 256, 0, stream>>>(ws_idx, out_enc);
    k_quant  <<<4096, 256, 0, stream>>>(inp, emb, ws_idx, out0, ws_loss);
    k_cluster<<<1, 1024, 0, stream>>>(ema_cs, ws_counts, ws_loss, out_cluster, out_loss, out_ent);
    k_fin    <<<1024, 256, 0, stream>>>(ema_w, out_cluster, out_neww, out_newemb);
}

// Round 6
// 730.176 us; speedup vs baseline: 1.0362x; 1.0362x over previous
//
#include <hip/hip_runtime.h>

// Problem constants
#define B_    64
#define C_    256
#define H_    32
#define W_    32
#define K_    1024
#define D_    256
#define HW_   1024
#define N_    65536
#define NELEM 16777216
#define DECAY_ 0.99f
#define OMD_   0.01f
#define EPS_   1e-5f
#define TAU_   0.05f        // fp64-rescan margin

// d_out float offsets
#define OFF_LOSS    16777216
#define OFF_ENT     16777217
#define OFF_ENC     16777218   // 8B-aligned only
#define OFF_CLUSTER 83886082
#define OFF_NEWW    83887106
#define OFF_NEWEMB  84149250

// Scratch inside the (later overwritten) encodings output region [OFF_ENC, OFF_ENC+67108864):
#define OFF_XHI     (OFF_ENC + 2)              // 16B-aligned; bf16 hi of -2x, [N][D] ushort
#define OFF_XLO     (OFF_XHI + 8388608)
#define OFF_EHI     (OFF_XLO + 8388608)        // bf16 hi of emb, PACKED B-fragment layout (see k_prep_e)
#define OFF_ELO     (OFF_EHI + 131072)
#define OFF_SORT2   (OFF_ELO + 131072)         // sorted[65536] | offsets[1025] | cursor[1024]
// Scratch ends at rel 17106947 (floats rel. to OFF_ENC). First 16B-aligned abs index after:
#define ZTAIL_ABS   33884168                   // = OFF_ENC + 17106950, abs%4==0
#define ZTAIL_F4    12500478                   // float4s in [rel 17106950, rel 67108862)
#define ZHEAD_F4    4276737                    // float4s in [rel 2, rel 17106950)

typedef __attribute__((ext_vector_type(8)))  short short8;
typedef __attribute__((ext_vector_type(16))) float floatx16;

__device__ __forceinline__ unsigned short f2bf(float f) {
    unsigned u = __float_as_uint(f);
    return (unsigned short)((u + 0x7fffu + ((u >> 16) & 1u)) >> 16);
}
__device__ __forceinline__ float bf2f(unsigned short h) {
    return __uint_as_float(((unsigned)h) << 16);
}

__global__ __launch_bounds__(256) void k_zero(float* __restrict__ dw, int* __restrict__ small_) {
    int g = blockIdx.x * 256 + threadIdx.x;
    dw[g] = 0.0f;                  // grid 1024*256 == 262144 == K*D exactly
    if (g < 1026) small_[g] = 0;   // counts[1024] + flagcount + losssum
}

// emb -> bf16 hi/lo + enorm.
// PACKED layout for MFMA B-fragments: tile = [K/32][ds=16][h=2][c32=32][j=8] ushorts,
// so a wave's load for a fixed (ds,h) is one contiguous 1KB transaction, and a
// whole 16KB tile is contiguous for global_load_lds staging.
// Element (k, d) lands at: tile(k>>5), ds=d>>4, h=(d>>3)&1, c32=k&31, j=d&7.
__global__ __launch_bounds__(64) void k_prep_e(const float* __restrict__ emb,
                                               unsigned short* __restrict__ ehi,
                                               unsigned short* __restrict__ elo,
                                               float* __restrict__ enorm) {
    const int k = blockIdx.x;
    const int t = threadIdx.x;       // handles d = 4t .. 4t+3 (same ds, same h)
    float4 v = ((const float4*)(emb + (size_t)k * D_))[t];
    float s = v.x * v.x + v.y * v.y + v.z * v.z + v.w * v.w;
    ushort4 hi, lo;
    {
        float f[4] = {v.x, v.y, v.z, v.w};
        unsigned short h[4], l[4];
        #pragma unroll
        for (int j = 0; j < 4; ++j) {
            h[j] = f2bf(f[j]);
            l[j] = f2bf(f[j] - bf2f(h[j]));
        }
        hi = make_ushort4(h[0], h[1], h[2], h[3]);
        lo = make_ushort4(l[0], l[1], l[2], l[3]);
    }
    // packed offset in ushorts:
    // (k>>5)*8192 + (t>>2)*512 + ((t>>1)&1)*256 + (k&31)*8 + (t&1)*4
    size_t o = ((size_t)(k >> 5) << 13) + ((size_t)(t >> 2) << 9)
             + (((size_t)(t >> 1) & 1) << 8) + ((size_t)(k & 31) << 3) + ((t & 1) << 2);
    *(ushort4*)(ehi + o) = hi;
    *(ushort4*)(elo + o) = lo;
    #pragma unroll
    for (int off = 32; off > 0; off >>= 1) s += __shfl_down(s, off);
    if (t == 0) enorm[k] = s;
}

// NCHW -> n-major bf16 hi/lo split of (-2x). Tile 32 d x 256 n per block.
__global__ __launch_bounds__(256) void k_prep_x(const float* __restrict__ inp,
                                                unsigned short* __restrict__ xhi,
                                                unsigned short* __restrict__ xlo) {
    __shared__ float tile[32][257];
    const int tid = threadIdx.x;
    const int bid = blockIdx.x;            // 2048 blocks: b(64) x hwtile(4) x dtile(8)
    const int dt = bid & 7;
    const int ht = (bid >> 3) & 3;
    const int b = bid >> 5;
    const int d0 = dt * 32;
    const int hw0 = ht * 256;
    const float* src = inp + (size_t)b * (C_ * HW_) + (size_t)d0 * HW_ + hw0;
    #pragma unroll
    for (int i = 0; i < 8; ++i) {
        int idx4 = i * 256 + tid;
        int dl = idx4 >> 6;
        int nl4 = (idx4 & 63) * 4;
        float4 v = *(const float4*)(src + (size_t)dl * HW_ + nl4);
        tile[dl][nl4] = v.x; tile[dl][nl4 + 1] = v.y;
        tile[dl][nl4 + 2] = v.z; tile[dl][nl4 + 3] = v.w;
    }
    __syncthreads();
    const int nbase = b * HW_ + hw0;
    #pragma unroll
    for (int i = 0; i < 4; ++i) {
        int f8 = i * 256 + tid;            // 1024 items of 8 d
        int nl = f8 >> 2;
        int dpos = (f8 & 3) * 8;
        union { unsigned short u[8]; short8 v; } ph, pl;
        #pragma unroll
        for (int j = 0; j < 8; ++j) {
            float f = -2.0f * tile[dpos + j][nl];
            unsigned short h = f2bf(f);
            ph.u[j] = h;
            pl.u[j] = f2bf(f - bf2f(h));
        }
        size_t o = (size_t)(nbase + nl) * D_ + d0 + dpos;
        *(short8*)(xhi + o) = ph.v;
        *(short8*)(xlo + o) = pl.v;
    }
}

// Stage one 16KB+16KB packed B tile into LDS via direct global->LDS DMA.
// 256 threads: 4 iters x 2 arrays = exactly 8 gload_lds instructions per thread.
__device__ __forceinline__ void stage_tile(const unsigned short* __restrict__ gh,
                                           const unsigned short* __restrict__ gl,
                                           unsigned short* sh, unsigned short* sl,
                                           int tid) {
    #pragma unroll
    for (int i = 0; i < 4; ++i) {
        __builtin_amdgcn_global_load_lds(
            (const __attribute__((address_space(1))) unsigned int*)(gh + i * 2048 + tid * 8),
            (__attribute__((address_space(3))) unsigned int*)(sh + i * 2048 + tid * 8),
            16, 0, 0);
        __builtin_amdgcn_global_load_lds(
            (const __attribute__((address_space(1))) unsigned int*)(gl + i * 2048 + tid * 8),
            (__attribute__((address_space(3))) unsigned int*)(sl + i * 2048 + tid * 8),
            16, 0, 0);
    }
}

// MFMA bf16x3 distance argmin on 32x32x16: 32 rows/wave, 32 cols/K-step.
// ROUND-4 structure (256 thr, 2 waves/SIMD, 2 acc chains, LDS dbuf) with ONE change:
// counted-vmcnt barrier. Per step each thread issues EXACTLY 8 gload_lds, then
// (order pinned by sched_barrier) EXACTLY 3 clamped zero-fill stores. At the step
// end, s_waitcnt vmcnt(3) = all staging loads complete, the 3 newest stores still
// in flight across the barrier -- store-ack latency leaves the critical path.
__global__ __launch_bounds__(256, 2) void k_argmin(
    const unsigned short* __restrict__ xhi, const unsigned short* __restrict__ xlo,
    const unsigned short* __restrict__ ehi, const unsigned short* __restrict__ elo,
    const float* __restrict__ enorm, int* __restrict__ idx_out,
    int* __restrict__ flagcount, int* __restrict__ flaglist,
    float4* __restrict__ encz)
{
    __shared__ unsigned short smem[2][2][8192];   // [buf][hi/lo][16KB] = 64KB
    const int tid = threadIdx.x;
    const int w = tid >> 6;
    const int lane = tid & 63;
    const int c32 = lane & 31;
    const int h = lane >> 5;
    const int r0 = blockIdx.x * 128 + w * 32;
    const int gtid = blockIdx.x * 256 + tid;      // 0..131071
    const float4 z4 = make_float4(0.f, 0.f, 0.f, 0.f);

    // A fragments: row m = lane&31, k = h*8 + j within each 16-chunk
    short8 Ahi[16], Alo[16];
    {
        const unsigned short* pa = xhi + (size_t)(r0 + c32) * D_ + h * 8;
        const unsigned short* pl = xlo + (size_t)(r0 + c32) * D_ + h * 8;
        #pragma unroll
        for (int ds = 0; ds < 16; ++ds) {
            Ahi[ds] = *(const short8*)(pa + ds * 16);
            Alo[ds] = *(const short8*)(pl + ds * 16);
        }
    }

    float b1[16], b2[16];
    int bi[16];
    #pragma unroll
    for (int i = 0; i < 16; ++i) { b1[i] = 3.0e38f; b2[i] = 3.0e38f; bi[i] = 0; }

    // prologue: stage tile 0 into buffer 0 (full drain barrier is fine once)
    stage_tile(ehi, elo, &smem[0][0][0], &smem[0][1][0], tid);
    __syncthreads();

    // per-lane read base within a staged tile: h*256 + c32*8 ushorts
    const int rb = (h << 8) + (c32 << 3);

    int cb = 0;
    for (int ct = 0; ct < 32; ++ct) {
        if (ct + 1 < 32) {
            stage_tile(ehi + (size_t)(ct + 1) * 8192, elo + (size_t)(ct + 1) * 8192,
                       &smem[cb ^ 1][0][0], &smem[cb ^ 1][1][0], tid);
        }
        // pin issue order: all 8 gloads BEFORE the 3 stores (vmcnt retires in order)
        __builtin_amdgcn_sched_barrier(0);
        // background zero-fill of the encodings tail: EXACTLY 3 stores, clamped
        // (131072 thr x 3 x 32 steps = 12.58M >= ZTAIL_F4; duplicates idempotent)
        #pragma unroll
        for (int jj = 0; jj < 3; ++jj) {
            int zi = (ct * 3 + jj) * 131072 + gtid;
            zi = (zi < ZTAIL_F4) ? zi : (ZTAIL_F4 - 1);
            encz[zi] = z4;
        }
        const int col = ct * 32 + c32;
        const float en = enorm[col];
        const unsigned short* sbh = &smem[cb][0][rb];
        const unsigned short* sbl = &smem[cb][1][rb];
        floatx16 hh, cr;
        #pragma unroll
        for (int i = 0; i < 16; ++i) { hh[i] = 0.0f; cr[i] = 0.0f; }
        #pragma unroll
        for (int ds = 0; ds < 16; ++ds) {
            short8 bh = *(const short8*)(sbh + ds * 512);
            short8 bl = *(const short8*)(sbl + ds * 512);
            hh = __builtin_amdgcn_mfma_f32_32x32x16_bf16(Ahi[ds], bh, hh, 0, 0, 0);
            cr = __builtin_amdgcn_mfma_f32_32x32x16_bf16(Ahi[ds], bl, cr, 0, 0, 0);
            cr = __builtin_amdgcn_mfma_f32_32x32x16_bf16(Alo[ds], bh, cr, 0, 0, 0);
        }
        #pragma unroll
        for (int r = 0; r < 16; ++r) {
            float v = hh[r] + cr[r] + en;
            bool lt = v < b1[r];
            float nb2 = lt ? b1[r] : fminf(v, b2[r]);   // med3(v, b1, b2)
            b2[r] = nb2;
            b1[r] = lt ? v : b1[r];
            bi[r] = lt ? col : bi[r];
        }
        // counted-vmcnt barrier: staging loads done, newest 3 stores stay in flight
        asm volatile("s_waitcnt vmcnt(3)" ::: "memory");
        __builtin_amdgcn_sched_barrier(0);
        __builtin_amdgcn_s_barrier();
        __builtin_amdgcn_sched_barrier(0);
        cb ^= 1;
    }

    // reduce each reg's (b1,b2,bi) across the 32 lanes sharing that row (c bits 0..4)
    #pragma unroll
    for (int r = 0; r < 16; ++r) {
        float B1 = b1[r], B2 = b2[r];
        int Bi = bi[r];
        #pragma unroll
        for (int mask = 1; mask <= 16; mask <<= 1) {
            float v1 = __shfl_xor(B1, mask);
            float v2 = __shfl_xor(B2, mask);
            int i1 = __shfl_xor(Bi, mask);
            if (v1 < B1 || (v1 == B1 && i1 < Bi)) {
                B2 = fminf(fminf(B1, B2), v2);
                B1 = v1; Bi = i1;
            } else {
                B2 = fminf(B2, fminf(v1, v2));
            }
        }
        if (c32 == 0) {
            int row = r0 + (r & 3) + 4 * h + 8 * (r >> 2);
            idx_out[row] = Bi;
            if (B2 - B1 < TAU_) {
                int p = atomicAdd(flagcount, 1);
                flaglist[p] = row;
            }
        }
    }
}

// Exact fp64 rescan of flagged (near-tie) rows.
__global__ __launch_bounds__(256) void k_rescan(
    const float* __restrict__ inp, const float* __restrict__ emb,
    const int* __restrict__ flagcount, const int* __restrict__ flaglist,
    int* __restrict__ idx_out)
{
    __shared__ double xd[256];
    __shared__ double sv[256];
    __shared__ int si[256];
    const int tid = threadIdx.x;
    const int nflag = *flagcount;
    for (int f = blockIdx.x; f < nflag; f += gridDim.x) {
        int n = flaglist[f];
        int b = n >> 10, nn = n & 1023;
        xd[tid] = (double)inp[(size_t)b * (C_ * HW_) + (size_t)tid * HW_ + nn];
        __syncthreads();
        double bv = 1e300; int bi = 0;
        for (int k = tid; k < K_; k += 256) {
            const float* ep = emb + (size_t)k * D_;
            double dot = 0.0, en = 0.0;
            for (int d = 0; d < D_; ++d) {
                double e = (double)ep[d];
                dot = fma(xd[d], e, dot);
                en  = fma(e, e, en);
            }
            double v = en - 2.0 * dot;
            if (v < bv) { bv = v; bi = k; }
        }
        sv[tid] = bv; si[tid] = bi;
        __syncthreads();
        for (int s = 128; s > 0; s >>= 1) {
            if (tid < s) {
                if (sv[tid + s] < sv[tid] || (sv[tid + s] == sv[tid] && si[tid + s] < si[tid])) {
                    sv[tid] = sv[tid + s]; si[tid] = si[tid + s];
                }
            }
            __syncthreads();
        }
        if (tid == 0) idx_out[n] = si[0];
        __syncthreads();
    }
}

__global__ __launch_bounds__(256) void k_hist(const int* __restrict__ idx, int* __restrict__ counts) {
    __shared__ int h[1024];
    const int tid = threadIdx.x;
    #pragma unroll
    for (int j = 0; j < 4; ++j) h[tid + j * 256] = 0;
    __syncthreads();
    #pragma unroll
    for (int j = 0; j < 4; ++j) {
        int n = blockIdx.x * 1024 + j * 256 + tid;
        atomicAdd(&h[idx[n]], 1);
    }
    __syncthreads();
    #pragma unroll
    for (int j = 0; j < 4; ++j) {
        int v = h[tid + j * 256];
        if (v) atomicAdd(&counts[tid + j * 256], v);
    }
}

__global__ __launch_bounds__(1024) void k_scan(const int* __restrict__ counts,
                                               int* __restrict__ offsets, int* __restrict__ cursor) {
    __shared__ int s[1024];
    const int t = threadIdx.x;
    const int c = counts[t];
    s[t] = c;
    __syncthreads();
    for (int off = 1; off < 1024; off <<= 1) {
        int v = (t >= off) ? s[t - off] : 0;
        __syncthreads();
        s[t] += v;
        __syncthreads();
    }
    int excl = s[t] - c;
    offsets[t] = excl;
    cursor[t] = excl;
    if (t == 1023) offsets[1024] = s[1023];
}

// Block-aggregated scatter.
__global__ __launch_bounds__(256) void k_scatter(const int* __restrict__ idx,
                                                 int* __restrict__ cursor, int* __restrict__ sorted) {
    __shared__ int hc[1024];
    __shared__ int hb[1024];
    const int tid = threadIdx.x;
    const int base = blockIdx.x * 1024;
    #pragma unroll
    for (int j = 0; j < 4; ++j) hc[tid + j * 256] = 0;
    __syncthreads();
    int myk[4], myn[4];
    #pragma unroll
    for (int j = 0; j < 4; ++j) {
        int n = base + j * 256 + tid;
        myn[j] = n;
        myk[j] = idx[n];
        atomicAdd(&hc[myk[j]], 1);
    }
    __syncthreads();
    #pragma unroll
    for (int j = 0; j < 4; ++j) {
        int kk = tid + j * 256;
        int c = hc[kk];
        hb[kk] = c ? atomicAdd(&cursor[kk], c) : 0;
    }
    __syncthreads();
    #pragma unroll
    for (int j = 0; j < 4; ++j) hc[tid + j * 256] = 0;
    __syncthreads();
    #pragma unroll
    for (int j = 0; j < 4; ++j) {
        int p = hb[myk[j]] + atomicAdd(&hc[myk[j]], 1);
        sorted[p] = myn[j];
    }
}

// Balanced segmented dw reduction reading xhi/xlo (x = -0.5*(hi+lo), exact to 2^-18).
__global__ __launch_bounds__(256) void k_dwg(const unsigned short* __restrict__ xhi,
                                             const unsigned short* __restrict__ xlo,
                                             const int* __restrict__ sorted,
                                             const int* __restrict__ idx,
                                             const int* __restrict__ offsets,
                                             float* __restrict__ dw) {
    const int lane = threadIdx.x & 63;
    const int wid = threadIdx.x >> 6;
    const int wbase = (blockIdx.x * 4 + wid) * 64;

    int myn = sorted[wbase + lane];
    int myk = idx[myn];

    float4 acc = make_float4(0.f, 0.f, 0.f, 0.f);
    int cur = __shfl(myk, 0);

    #pragma unroll 8
    for (int i = 0; i < 64; ++i) {
        int n = __shfl(myn, i);
        int k = __shfl(myk, i);
        if (k != cur) {
            bool full = (offsets[cur] >= wbase) && (offsets[cur + 1] <= wbase + 64);
            float* dwk = dw + (size_t)cur * D_ + lane * 4;
            if (full) {
                ((float2*)dwk)[0] = make_float2(-0.5f * acc.x, -0.5f * acc.y);
                ((float2*)dwk)[1] = make_float2(-0.5f * acc.z, -0.5f * acc.w);
            } else {
                atomicAdd(dwk + 0, -0.5f * acc.x);
                atomicAdd(dwk + 1, -0.5f * acc.y);
                atomicAdd(dwk + 2, -0.5f * acc.z);
                atomicAdd(dwk + 3, -0.5f * acc.w);
            }
            acc = make_float4(0.f, 0.f, 0.f, 0.f);
            cur = k;
        }
        size_t o = (size_t)n * D_ + lane * 4;
        ushort4 hx = *(const ushort4*)(xhi + o);
        ushort4 lx = *(const ushort4*)(xlo + o);
        acc.x += bf2f(hx.x) + bf2f(lx.x);
        acc.y += bf2f(hx.y) + bf2f(lx.y);
        acc.z += bf2f(hx.z) + bf2f(lx.z);
        acc.w += bf2f(hx.w) + bf2f(lx.w);
    }
    {
        bool full = (offsets[cur] >= wbase) && (offsets[cur + 1] <= wbase + 64);
        float* dwk = dw + (size_t)cur * D_ + lane * 4;
        if (full) {
            ((float2*)dwk)[0] = make_float2(-0.5f * acc.x, -0.5f * acc.y);
            ((float2*)dwk)[1] = make_float2(-0.5f * acc.z, -0.5f * acc.w);
        } else {
            atomicAdd(dwk + 0, -0.5f * acc.x);
            atomicAdd(dwk + 1, -0.5f * acc.y);
            atomicAdd(dwk + 2, -0.5f * acc.z);
            atomicAdd(dwk + 3, -0.5f * acc.w);
        }
    }
}

// Zero only the scratch-occupied head of encodings (the 200MB tail was zeroed
// inside k_argmin). Region [OFF_ENC+2, OFF_ENC+17106950) as float4 + head/tail scalars.
__global__ __launch_bounds__(256) void k_enc0(float* __restrict__ enc) {
    const float4 z = make_float4(0.f, 0.f, 0.f, 0.f);
    float4* p = (float4*)(enc + 2);
    int t = blockIdx.x * 256 + threadIdx.x;     // 4096*256 = 1048576 threads
    #pragma unroll
    for (int it = 0; it < 5; ++it) {
        int i = it * 1048576 + t;
        if (i < ZHEAD_F4) p[i] = z;
    }
    if (t == 0) { enc[0] = 0.f; enc[1] = 0.f; enc[67108862] = 0.f; enc[67108863] = 0.f; }
}

__global__ __launch_bounds__(256) void k_enc1(const int* __restrict__ idx, float* __restrict__ enc) {
    #pragma unroll
    for (int j = 0; j < 4; ++j) {
        int n = blockIdx.x * 1024 + j * 256 + threadIdx.x;
        enc[(size_t)n * 1024 + idx[n]] = 1.0f;
    }
}

__global__ __launch_bounds__(256) void k_quant(
    const float* __restrict__ inp, const float* __restrict__ emb,
    const int* __restrict__ idx, float* __restrict__ outp, float* __restrict__ losssum)
{
    __shared__ float red[256];
    const int tid = threadIdx.x;
    float s = 0.0f;
    const int base = blockIdx.x * 1024;
    #pragma unroll
    for (int it = 0; it < 4; ++it) {
        int g = base + it * 256 + tid;
        int o = g << 2;
        int b = o >> 18;
        int c = (o >> 10) & 255;
        int hw = o & 1023;
        int n = (b << 10) + hw;
        float4 x = ((const float4*)inp)[g];
        int4 ki = *(const int4*)(idx + n);
        float q0 = emb[(size_t)ki.x * D_ + c];
        float q1 = emb[(size_t)ki.y * D_ + c];
        float q2 = emb[(size_t)ki.z * D_ + c];
        float q3 = emb[(size_t)ki.w * D_ + c];
        float d0 = q0 - x.x, d1 = q1 - x.y, d2 = q2 - x.z, d3 = q3 - x.w;
        ((float4*)outp)[g] = make_float4(x.x + d0, x.y + d1, x.z + d2, x.w + d3);
        s += d0 * d0 + d1 * d1 + d2 * d2 + d3 * d3;
    }
    red[tid] = s;
    __syncthreads();
    for (int t = 128; t > 0; t >>= 1) {
        if (tid < t) red[tid] += red[tid + t];
        __syncthreads();
    }
    if (tid == 0) atomicAdd(losssum, red[0]);
}

__global__ __launch_bounds__(1024) void k_cluster(
    const float* __restrict__ ema_cs, const int* __restrict__ counts,
    const float* __restrict__ losssum, float* __restrict__ out_cluster,
    float* __restrict__ out_loss, float* __restrict__ out_ent)
{
    __shared__ float red[1024];
    const int k = threadIdx.x;
    float cnt = (float)counts[k];
    float raw = ema_cs[k] * DECAY_ + OMD_ * cnt;
    red[k] = raw;
    __syncthreads();
    for (int t = 512; t > 0; t >>= 1) {
        if (k < t) red[k] += red[k + t];
        __syncthreads();
    }
    float nsum = red[0];
    __syncthreads();
    float clv = (raw + EPS_) / (nsum + 1024.0f * EPS_) * nsum;
    out_cluster[k] = clv;
    float p = cnt * (1.0f / 65536.0f);
    red[k] = p * logf(p + 1e-10f);
    __syncthreads();
    for (int t = 512; t > 0; t >>= 1) {
        if (k < t) red[k] += red[k + t];
        __syncthreads();
    }
    if (k == 0) {
        out_ent[0] = -red[0];
        out_loss[0] = 0.25f * losssum[0] * (1.0f / 16777216.0f);
    }
}

__global__ __launch_bounds__(256) void k_fin(
    const float* __restrict__ ema_w, const float* __restrict__ cluster,
    float* __restrict__ neww, float* __restrict__ newemb)
{
    int g = blockIdx.x * 256 + threadIdx.x;
    int k = g >> 8;
    float w = ema_w[g] * DECAY_ + OMD_ * neww[g];   // neww currently holds dw
    neww[g] = w;
    newemb[g] = w / cluster[k];
}

extern "C" void kernel_launch(void* const* d_in, const int* in_sizes, int n_in,
                              void* d_out, int out_size, void* d_ws, size_t ws_size,
                              hipStream_t stream)
{
    const float* inp    = (const float*)d_in[0];
    const float* emb    = (const float*)d_in[1];
    const float* ema_cs = (const float*)d_in[2];
    const float* ema_w  = (const float*)d_in[3];

    float* out0        = (float*)d_out;
    float* out_loss    = out0 + OFF_LOSS;
    float* out_ent     = out0 + OFF_ENT;
    float* out_enc     = out0 + OFF_ENC;
    float* out_cluster = out0 + OFF_CLUSTER;
    float* out_neww    = out0 + OFF_NEWW;
    float* out_newemb  = out0 + OFF_NEWEMB;

    unsigned short* ws_xhi  = (unsigned short*)(out0 + OFF_XHI);
    unsigned short* ws_xlo  = (unsigned short*)(out0 + OFF_XLO);
    unsigned short* ws_ehi  = (unsigned short*)(out0 + OFF_EHI);
    unsigned short* ws_elo  = (unsigned short*)(out0 + OFF_ELO);
    int*   ws_sorted  = (int*)(out0 + OFF_SORT2);
    int*   ws_offsets = ws_sorted + 65536;
    int*   ws_cursor  = ws_offsets + 1025;

    int*   ws_idx    = (int*)d_ws;
    int*   ws_counts = ws_idx + 65536;
    int*   ws_flagc  = ws_idx + 66560;
    float* ws_loss   = (float*)(ws_idx + 66561);
    int*   ws_flagl  = ws_idx + 66562;
    float* ws_enorm  = (float*)(ws_idx + 132098);

    float4* encz = (float4*)(out0 + ZTAIL_ABS);

    k_zero   <<<1024, 256, 0, stream>>>(out_neww, ws_counts);
    k_prep_e <<<1024, 64, 0, stream>>>(emb, ws_ehi, ws_elo, ws_enorm);
    k_prep_x <<<2048, 256, 0, stream>>>(inp, ws_xhi, ws_xlo);
    k_argmin <<<512, 256, 0, stream>>>(ws_xhi, ws_xlo, ws_ehi, ws_elo, ws_enorm,
                                       ws_idx, ws_flagc, ws_flagl, encz);
    k_rescan <<<256, 256, 0, stream>>>(inp, emb, ws_flagc, ws_flagl, ws_idx);
    k_hist   <<<64, 256, 0, stream>>>(ws_idx, ws_counts);
    k_scan   <<<1, 1024, 0, stream>>>(ws_counts, ws_offsets, ws_cursor);
    k_scatter<<<64, 256, 0, stream>>>(ws_idx, ws_cursor, ws_sorted);
    k_dwg    <<<256, 256, 0, stream>>>(ws_xhi, ws_xlo, ws_sorted, ws_idx, ws_offsets, out_neww);
    k_enc0   <<<4096, 256, 0, stream>>>(out_enc);
    k_enc1   <<<64, 256, 0, stream>>>(ws_idx, out_enc);
    k_quant  <<<4096, 256, 0, stream>>>(inp, emb, ws_idx, out0, ws_loss);
    k_cluster<<<1, 1024, 0, stream>>>(ema_cs, ws_counts, ws_loss, out_cluster, out_loss, out_ent);
    k_fin    <<<1024, 256, 0, stream>>>(ema_w, out_cluster, out_neww, out_newemb);
}

// Round 7
// 662.251 us; speedup vs baseline: 1.1425x; 1.1026x over previous
//
#include <hip/hip_runtime.h>

// Problem constants
#define B_    64
#define C_    256
#define H_    32
#define W_    32
#define K_    1024
#define D_    256
#define HW_   1024
#define N_    65536
#define NELEM 16777216
#define DECAY_ 0.99f
#define OMD_   0.01f
#define EPS_   1e-5f
#define TAU_   0.05f        // fp64-rescan margin

// d_out float offsets
#define OFF_LOSS    16777216
#define OFF_ENT     16777217
#define OFF_ENC     16777218   // 8B-aligned only
#define OFF_CLUSTER 83886082
#define OFF_NEWW    83887106
#define OFF_NEWEMB  84149250

// Scratch inside the (later overwritten) encodings output region [OFF_ENC, OFF_ENC+67108864):
#define OFF_XHI     (OFF_ENC + 2)              // 16B-aligned; bf16 hi of -2x, [N][D] ushort
#define OFF_XLO     (OFF_XHI + 8388608)
#define OFF_EHI     (OFF_XLO + 8388608)        // bf16 hi of emb, PACKED B-fragment layout (see k_prep_e)
#define OFF_ELO     (OFF_EHI + 131072)
#define OFF_SORT2   (OFF_ELO + 131072)         // sorted[65536] | offsets[1025] | cursor[1024]
// Scratch ends at rel 17106947 (floats rel. to OFF_ENC). First 16B-aligned abs index after:
#define ZTAIL_ABS   33884168                   // = OFF_ENC + 17106950, abs%4==0
#define ZTAIL_F4    12500478                   // float4s in [rel 17106950, rel 67108862)
#define ZHEAD_F4    4276737                    // float4s in [rel 2, rel 17106950)

typedef __attribute__((ext_vector_type(8)))  short short8;
typedef __attribute__((ext_vector_type(16))) float floatx16;

__device__ __forceinline__ unsigned short f2bf(float f) {
    unsigned u = __float_as_uint(f);
    return (unsigned short)((u + 0x7fffu + ((u >> 16) & 1u)) >> 16);
}
__device__ __forceinline__ float bf2f(unsigned short h) {
    return __uint_as_float(((unsigned)h) << 16);
}

// emb -> bf16 hi/lo + enorm.
// PACKED layout for MFMA B-fragments: tile = [K/32][ds=16][h=2][c32=32][j=8] ushorts,
// so a wave's load for a fixed (ds,h) is one contiguous 1KB transaction, and a
// whole 16KB tile is contiguous for global_load_lds staging.
__global__ __launch_bounds__(64) void k_prep_e(const float* __restrict__ emb,
                                               unsigned short* __restrict__ ehi,
                                               unsigned short* __restrict__ elo,
                                               float* __restrict__ enorm) {
    const int k = blockIdx.x;
    const int t = threadIdx.x;       // handles d = 4t .. 4t+3 (same ds, same h)
    float4 v = ((const float4*)(emb + (size_t)k * D_))[t];
    float s = v.x * v.x + v.y * v.y + v.z * v.z + v.w * v.w;
    ushort4 hi, lo;
    {
        float f[4] = {v.x, v.y, v.z, v.w};
        unsigned short h[4], l[4];
        #pragma unroll
        for (int j = 0; j < 4; ++j) {
            h[j] = f2bf(f[j]);
            l[j] = f2bf(f[j] - bf2f(h[j]));
        }
        hi = make_ushort4(h[0], h[1], h[2], h[3]);
        lo = make_ushort4(l[0], l[1], l[2], l[3]);
    }
    size_t o = ((size_t)(k >> 5) << 13) + ((size_t)(t >> 2) << 9)
             + (((size_t)(t >> 1) & 1) << 8) + ((size_t)(k & 31) << 3) + ((t & 1) << 2);
    *(ushort4*)(ehi + o) = hi;
    *(ushort4*)(elo + o) = lo;
    #pragma unroll
    for (int off = 32; off > 0; off >>= 1) s += __shfl_down(s, off);
    if (t == 0) enorm[k] = s;
}

// NCHW -> n-major bf16 hi/lo split of (-2x). Tile 32 d x 256 n per block.
// ALSO (folded k_zero): first 1024 blocks zero dw[262144] and the small counters.
__global__ __launch_bounds__(256) void k_prep_x(const float* __restrict__ inp,
                                                unsigned short* __restrict__ xhi,
                                                unsigned short* __restrict__ xlo,
                                                float* __restrict__ dw,
                                                int* __restrict__ small_) {
    __shared__ float tile[32][257];
    const int tid = threadIdx.x;
    const int bid = blockIdx.x;            // 2048 blocks: b(64) x hwtile(4) x dtile(8)
    if (bid < 1024) {
        int g = bid * 256 + tid;
        dw[g] = 0.0f;                      // 1024*256 == K*D exactly
        if (g < 1026) small_[g] = 0;       // counts[1024] + flagcount + losssum
    }
    const int dt = bid & 7;
    const int ht = (bid >> 3) & 3;
    const int b = bid >> 5;
    const int d0 = dt * 32;
    const int hw0 = ht * 256;
    const float* src = inp + (size_t)b * (C_ * HW_) + (size_t)d0 * HW_ + hw0;
    #pragma unroll
    for (int i = 0; i < 8; ++i) {
        int idx4 = i * 256 + tid;
        int dl = idx4 >> 6;
        int nl4 = (idx4 & 63) * 4;
        float4 v = *(const float4*)(src + (size_t)dl * HW_ + nl4);
        tile[dl][nl4] = v.x; tile[dl][nl4 + 1] = v.y;
        tile[dl][nl4 + 2] = v.z; tile[dl][nl4 + 3] = v.w;
    }
    __syncthreads();
    const int nbase = b * HW_ + hw0;
    #pragma unroll
    for (int i = 0; i < 4; ++i) {
        int f8 = i * 256 + tid;            // 1024 items of 8 d
        int nl = f8 >> 2;
        int dpos = (f8 & 3) * 8;
        union { unsigned short u[8]; short8 v; } ph, pl;
        #pragma unroll
        for (int j = 0; j < 8; ++j) {
            float f = -2.0f * tile[dpos + j][nl];
            unsigned short h = f2bf(f);
            ph.u[j] = h;
            pl.u[j] = f2bf(f - bf2f(h));
        }
        size_t o = (size_t)(nbase + nl) * D_ + d0 + dpos;
        *(short8*)(xhi + o) = ph.v;
        *(short8*)(xlo + o) = pl.v;
    }
}

// Stage one 16KB+16KB packed B tile into LDS via direct global->LDS DMA.
// 256 threads: 4 iters x 2 arrays = exactly 8 gload_lds instructions per thread.
__device__ __forceinline__ void stage_tile(const unsigned short* __restrict__ gh,
                                           const unsigned short* __restrict__ gl,
                                           unsigned short* sh, unsigned short* sl,
                                           int tid) {
    #pragma unroll
    for (int i = 0; i < 4; ++i) {
        __builtin_amdgcn_global_load_lds(
            (const __attribute__((address_space(1))) unsigned int*)(gh + i * 2048 + tid * 8),
            (__attribute__((address_space(3))) unsigned int*)(sh + i * 2048 + tid * 8),
            16, 0, 0);
        __builtin_amdgcn_global_load_lds(
            (const __attribute__((address_space(1))) unsigned int*)(gl + i * 2048 + tid * 8),
            (__attribute__((address_space(3))) unsigned int*)(sl + i * 2048 + tid * 8),
            16, 0, 0);
    }
}

// MFMA bf16x3 distance argmin on 32x32x16: 32 rows/wave, 32 cols/K-step.
// 256 thr, 2 waves/SIMD, 2 acc chains, LDS dbuf, counted-vmcnt barrier (round-6 proven).
__global__ __launch_bounds__(256, 2) void k_argmin(
    const unsigned short* __restrict__ xhi, const unsigned short* __restrict__ xlo,
    const unsigned short* __restrict__ ehi, const unsigned short* __restrict__ elo,
    const float* __restrict__ enorm, int* __restrict__ idx_out,
    int* __restrict__ flagcount, int* __restrict__ flaglist,
    float4* __restrict__ encz)
{
    __shared__ unsigned short smem[2][2][8192];   // [buf][hi/lo][16KB] = 64KB
    const int tid = threadIdx.x;
    const int w = tid >> 6;
    const int lane = tid & 63;
    const int c32 = lane & 31;
    const int h = lane >> 5;
    const int r0 = blockIdx.x * 128 + w * 32;
    const int gtid = blockIdx.x * 256 + tid;      // 0..131071
    const float4 z4 = make_float4(0.f, 0.f, 0.f, 0.f);

    // A fragments: row m = lane&31, k = h*8 + j within each 16-chunk
    short8 Ahi[16], Alo[16];
    {
        const unsigned short* pa = xhi + (size_t)(r0 + c32) * D_ + h * 8;
        const unsigned short* pl = xlo + (size_t)(r0 + c32) * D_ + h * 8;
        #pragma unroll
        for (int ds = 0; ds < 16; ++ds) {
            Ahi[ds] = *(const short8*)(pa + ds * 16);
            Alo[ds] = *(const short8*)(pl + ds * 16);
        }
    }

    float b1[16], b2[16];
    int bi[16];
    #pragma unroll
    for (int i = 0; i < 16; ++i) { b1[i] = 3.0e38f; b2[i] = 3.0e38f; bi[i] = 0; }

    // prologue: stage tile 0 into buffer 0 (full drain barrier is fine once)
    stage_tile(ehi, elo, &smem[0][0][0], &smem[0][1][0], tid);
    __syncthreads();

    // per-lane read base within a staged tile: h*256 + c32*8 ushorts
    const int rb = (h << 8) + (c32 << 3);

    int cb = 0;
    for (int ct = 0; ct < 32; ++ct) {
        if (ct + 1 < 32) {
            stage_tile(ehi + (size_t)(ct + 1) * 8192, elo + (size_t)(ct + 1) * 8192,
                       &smem[cb ^ 1][0][0], &smem[cb ^ 1][1][0], tid);
        }
        // pin issue order: all 8 gloads BEFORE the 3 stores (vmcnt retires in order)
        __builtin_amdgcn_sched_barrier(0);
        // background zero-fill of the encodings tail: EXACTLY 3 stores, clamped
        #pragma unroll
        for (int jj = 0; jj < 3; ++jj) {
            int zi = (ct * 3 + jj) * 131072 + gtid;
            zi = (zi < ZTAIL_F4) ? zi : (ZTAIL_F4 - 1);
            encz[zi] = z4;
        }
        const int col = ct * 32 + c32;
        const float en = enorm[col];
        const unsigned short* sbh = &smem[cb][0][rb];
        const unsigned short* sbl = &smem[cb][1][rb];
        floatx16 hh, cr;
        #pragma unroll
        for (int i = 0; i < 16; ++i) { hh[i] = 0.0f; cr[i] = 0.0f; }
        #pragma unroll
        for (int ds = 0; ds < 16; ++ds) {
            short8 bh = *(const short8*)(sbh + ds * 512);
            short8 bl = *(const short8*)(sbl + ds * 512);
            hh = __builtin_amdgcn_mfma_f32_32x32x16_bf16(Ahi[ds], bh, hh, 0, 0, 0);
            cr = __builtin_amdgcn_mfma_f32_32x32x16_bf16(Ahi[ds], bl, cr, 0, 0, 0);
            cr = __builtin_amdgcn_mfma_f32_32x32x16_bf16(Alo[ds], bh, cr, 0, 0, 0);
        }
        #pragma unroll
        for (int r = 0; r < 16; ++r) {
            float v = hh[r] + cr[r] + en;
            bool lt = v < b1[r];
            float nb2 = lt ? b1[r] : fminf(v, b2[r]);   // med3(v, b1, b2)
            b2[r] = nb2;
            b1[r] = lt ? v : b1[r];
            bi[r] = lt ? col : bi[r];
        }
        // counted-vmcnt barrier: staging loads done, newest 3 stores stay in flight
        asm volatile("s_waitcnt vmcnt(3)" ::: "memory");
        __builtin_amdgcn_sched_barrier(0);
        __builtin_amdgcn_s_barrier();
        __builtin_amdgcn_sched_barrier(0);
        cb ^= 1;
    }

    // reduce each reg's (b1,b2,bi) across the 32 lanes sharing that row (c bits 0..4)
    #pragma unroll
    for (int r = 0; r < 16; ++r) {
        float B1 = b1[r], B2 = b2[r];
        int Bi = bi[r];
        #pragma unroll
        for (int mask = 1; mask <= 16; mask <<= 1) {
            float v1 = __shfl_xor(B1, mask);
            float v2 = __shfl_xor(B2, mask);
            int i1 = __shfl_xor(Bi, mask);
            if (v1 < B1 || (v1 == B1 && i1 < Bi)) {
                B2 = fminf(fminf(B1, B2), v2);
                B1 = v1; Bi = i1;
            } else {
                B2 = fminf(B2, fminf(v1, v2));
            }
        }
        if (c32 == 0) {
            int row = r0 + (r & 3) + 4 * h + 8 * (r >> 2);
            idx_out[row] = Bi;
            if (B2 - B1 < TAU_) {
                int p = atomicAdd(flagcount, 1);
                flaglist[p] = row;
            }
        }
    }
}

// Exact fp64 rescan of flagged (near-tie) rows.
__global__ __launch_bounds__(256) void k_rescan(
    const float* __restrict__ inp, const float* __restrict__ emb,
    const int* __restrict__ flagcount, const int* __restrict__ flaglist,
    int* __restrict__ idx_out)
{
    __shared__ double xd[256];
    __shared__ double sv[256];
    __shared__ int si[256];
    const int tid = threadIdx.x;
    const int nflag = *flagcount;
    for (int f = blockIdx.x; f < nflag; f += gridDim.x) {
        int n = flaglist[f];
        int b = n >> 10, nn = n & 1023;
        xd[tid] = (double)inp[(size_t)b * (C_ * HW_) + (size_t)tid * HW_ + nn];
        __syncthreads();
        double bv = 1e300; int bi = 0;
        for (int k = tid; k < K_; k += 256) {
            const float* ep = emb + (size_t)k * D_;
            double dot = 0.0, en = 0.0;
            for (int d = 0; d < D_; ++d) {
                double e = (double)ep[d];
                dot = fma(xd[d], e, dot);
                en  = fma(e, e, en);
            }
            double v = en - 2.0 * dot;
            if (v < bv) { bv = v; bi = k; }
        }
        sv[tid] = bv; si[tid] = bi;
        __syncthreads();
        for (int s = 128; s > 0; s >>= 1) {
            if (tid < s) {
                if (sv[tid + s] < sv[tid] || (sv[tid + s] == sv[tid] && si[tid + s] < si[tid])) {
                    sv[tid] = sv[tid + s]; si[tid] = si[tid + s];
                }
            }
            __syncthreads();
        }
        if (tid == 0) idx_out[n] = si[0];
        __syncthreads();
    }
}

__global__ __launch_bounds__(256) void k_hist(const int* __restrict__ idx, int* __restrict__ counts) {
    __shared__ int h[1024];
    const int tid = threadIdx.x;
    #pragma unroll
    for (int j = 0; j < 4; ++j) h[tid + j * 256] = 0;
    __syncthreads();
    #pragma unroll
    for (int j = 0; j < 4; ++j) {
        int n = blockIdx.x * 1024 + j * 256 + tid;
        atomicAdd(&h[idx[n]], 1);
    }
    __syncthreads();
    #pragma unroll
    for (int j = 0; j < 4; ++j) {
        int v = h[tid + j * 256];
        if (v) atomicAdd(&counts[tid + j * 256], v);
    }
}

__global__ __launch_bounds__(1024) void k_scan(const int* __restrict__ counts,
                                               int* __restrict__ offsets, int* __restrict__ cursor) {
    __shared__ int s[1024];
    const int t = threadIdx.x;
    const int c = counts[t];
    s[t] = c;
    __syncthreads();
    for (int off = 1; off < 1024; off <<= 1) {
        int v = (t >= off) ? s[t - off] : 0;
        __syncthreads();
        s[t] += v;
        __syncthreads();
    }
    int excl = s[t] - c;
    offsets[t] = excl;
    cursor[t] = excl;
    if (t == 1023) offsets[1024] = s[1023];
}

// Block-aggregated scatter.
__global__ __launch_bounds__(256) void k_scatter(const int* __restrict__ idx,
                                                 int* __restrict__ cursor, int* __restrict__ sorted) {
    __shared__ int hc[1024];
    __shared__ int hb[1024];
    const int tid = threadIdx.x;
    const int base = blockIdx.x * 1024;
    #pragma unroll
    for (int j = 0; j < 4; ++j) hc[tid + j * 256] = 0;
    __syncthreads();
    int myk[4], myn[4];
    #pragma unroll
    for (int j = 0; j < 4; ++j) {
        int n = base + j * 256 + tid;
        myn[j] = n;
        myk[j] = idx[n];
        atomicAdd(&hc[myk[j]], 1);
    }
    __syncthreads();
    #pragma unroll
    for (int j = 0; j < 4; ++j) {
        int kk = tid + j * 256;
        int c = hc[kk];
        hb[kk] = c ? atomicAdd(&cursor[kk], c) : 0;
    }
    __syncthreads();
    #pragma unroll
    for (int j = 0; j < 4; ++j) hc[tid + j * 256] = 0;
    __syncthreads();
    #pragma unroll
    for (int j = 0; j < 4; ++j) {
        int p = hb[myk[j]] + atomicAdd(&hc[myk[j]], 1);
        sorted[p] = myn[j];
    }
}

// Balanced segmented dw reduction reading xhi/xlo (x = -0.5*(hi+lo), exact to 2^-18).
__global__ __launch_bounds__(256) void k_dwg(const unsigned short* __restrict__ xhi,
                                             const unsigned short* __restrict__ xlo,
                                             const int* __restrict__ sorted,
                                             const int* __restrict__ idx,
                                             const int* __restrict__ offsets,
                                             float* __restrict__ dw) {
    const int lane = threadIdx.x & 63;
    const int wid = threadIdx.x >> 6;
    const int wbase = (blockIdx.x * 4 + wid) * 64;

    int myn = sorted[wbase + lane];
    int myk = idx[myn];

    float4 acc = make_float4(0.f, 0.f, 0.f, 0.f);
    int cur = __shfl(myk, 0);

    #pragma unroll 8
    for (int i = 0; i < 64; ++i) {
        int n = __shfl(myn, i);
        int k = __shfl(myk, i);
        if (k != cur) {
            bool full = (offsets[cur] >= wbase) && (offsets[cur + 1] <= wbase + 64);
            float* dwk = dw + (size_t)cur * D_ + lane * 4;
            if (full) {
                ((float2*)dwk)[0] = make_float2(-0.5f * acc.x, -0.5f * acc.y);
                ((float2*)dwk)[1] = make_float2(-0.5f * acc.z, -0.5f * acc.w);
            } else {
                atomicAdd(dwk + 0, -0.5f * acc.x);
                atomicAdd(dwk + 1, -0.5f * acc.y);
                atomicAdd(dwk + 2, -0.5f * acc.z);
                atomicAdd(dwk + 3, -0.5f * acc.w);
            }
            acc = make_float4(0.f, 0.f, 0.f, 0.f);
            cur = k;
        }
        size_t o = (size_t)n * D_ + lane * 4;
        ushort4 hx = *(const ushort4*)(xhi + o);
        ushort4 lx = *(const ushort4*)(xlo + o);
        acc.x += bf2f(hx.x) + bf2f(lx.x);
        acc.y += bf2f(hx.y) + bf2f(lx.y);
        acc.z += bf2f(hx.z) + bf2f(lx.z);
        acc.w += bf2f(hx.w) + bf2f(lx.w);
    }
    {
        bool full = (offsets[cur] >= wbase) && (offsets[cur + 1] <= wbase + 64);
        float* dwk = dw + (size_t)cur * D_ + lane * 4;
        if (full) {
            ((float2*)dwk)[0] = make_float2(-0.5f * acc.x, -0.5f * acc.y);
            ((float2*)dwk)[1] = make_float2(-0.5f * acc.z, -0.5f * acc.w);
        } else {
            atomicAdd(dwk + 0, -0.5f * acc.x);
            atomicAdd(dwk + 1, -0.5f * acc.y);
            atomicAdd(dwk + 2, -0.5f * acc.z);
            atomicAdd(dwk + 3, -0.5f * acc.w);
        }
    }
}

// Quantize + loss (LDS-transposed embedding gather) + folded head-zero of the
// scratch region. Block = (batch b, 64-wide hw tile): gathers the 64 needed emb
// rows coalesced into LDS, then writes NCHW-coalesced float4 outputs.
// One-hot writes stay in k_enc1 (separate kernel AFTER this one -- intra-kernel
// they would race with the head-zero stores).
__global__ __launch_bounds__(256) void k_quant(
    const float* __restrict__ inp, const float* __restrict__ emb,
    const int* __restrict__ idx, float* __restrict__ outp, float* __restrict__ losssum,
    float* __restrict__ enc)
{
    __shared__ float qt[64][260];      // [n_local][c], pad 260 -> conflict-free b128 writes
    __shared__ int karr[64];
    __shared__ float red[256];
    const int tid = threadIdx.x;
    const int bid = blockIdx.x;        // 1024 blocks: b(64) x hwtile(16)
    const int b = bid >> 4;
    const int ht = bid & 15;
    const int base_n = b * HW_ + ht * 64;

    // folded head-zero: [OFF_ENC+2, OFF_ENC+17106950) as float4, fire-and-forget
    {
        const float4 z4 = make_float4(0.f, 0.f, 0.f, 0.f);
        float4* pz = (float4*)(enc + 2);
        int t = bid * 256 + tid;       // 262144 threads
        #pragma unroll
        for (int it = 0; it < 17; ++it) {
            int i = it * 262144 + t;
            if (i < ZHEAD_F4) pz[i] = z4;
        }
        if (t == 0) { enc[0] = 0.f; enc[1] = 0.f; enc[67108862] = 0.f; enc[67108863] = 0.f; }
    }

    if (tid < 64) karr[tid] = idx[base_n + tid];
    __syncthreads();

    // gather 64 emb rows into LDS, coalesced: 16 float4 per thread, 64 threads/row
    #pragma unroll
    for (int it = 0; it < 16; ++it) {
        int f = it * 256 + tid;        // 0..4095
        int r = f >> 6;                // row 0..63
        int c4 = (f & 63) << 2;        // col 0,4,...,252
        float4 v = ((const float4*)emb)[karr[r] * 64 + (c4 >> 2)];
        *(float4*)(&qt[r][c4]) = v;    // row-contiguous across the wave: conflict-free
    }
    __syncthreads();

    // emit: thread handles (c, 4 consecutive hw): coalesced 256B chunks
    float s = 0.0f;
    #pragma unroll
    for (int it = 0; it < 16; ++it) {
        int f = it * 256 + tid;        // 0..4095
        int c = f >> 4;                // 0..255
        int hl = (f & 15) << 2;        // hw_local 0,4,...,60
        int g = b * 65536 + c * 256 + ht * 16 + (hl >> 2);   // float4 index
        float4 x = ((const float4*)inp)[g];
        float q0 = qt[hl + 0][c];
        float q1 = qt[hl + 1][c];
        float q2 = qt[hl + 2][c];
        float q3 = qt[hl + 3][c];
        float d0 = q0 - x.x, d1 = q1 - x.y, d2 = q2 - x.z, d3 = q3 - x.w;
        ((float4*)outp)[g] = make_float4(x.x + d0, x.y + d1, x.z + d2, x.w + d3);
        s += d0 * d0 + d1 * d1 + d2 * d2 + d3 * d3;
    }
    red[tid] = s;
    __syncthreads();
    for (int t = 128; t > 0; t >>= 1) {
        if (tid < t) red[tid] += red[tid + t];
        __syncthreads();
    }
    if (tid == 0) atomicAdd(losssum, red[0]);
}

__global__ __launch_bounds__(256) void k_enc1(const int* __restrict__ idx, float* __restrict__ enc) {
    #pragma unroll
    for (int j = 0; j < 4; ++j) {
        int n = blockIdx.x * 1024 + j * 256 + threadIdx.x;
        enc[(size_t)n * 1024 + idx[n]] = 1.0f;
    }
}

__global__ __launch_bounds__(1024) void k_cluster(
    const float* __restrict__ ema_cs, const int* __restrict__ counts,
    const float* __restrict__ losssum, float* __restrict__ out_cluster,
    float* __restrict__ out_loss, float* __restrict__ out_ent)
{
    __shared__ float red[1024];
    const int k = threadIdx.x;
    float cnt = (float)counts[k];
    float raw = ema_cs[k] * DECAY_ + OMD_ * cnt;
    red[k] = raw;
    __syncthreads();
    for (int t = 512; t > 0; t >>= 1) {
        if (k < t) red[k] += red[k + t];
        __syncthreads();
    }
    float nsum = red[0];
    __syncthreads();
    float clv = (raw + EPS_) / (nsum + 1024.0f * EPS_) * nsum;
    out_cluster[k] = clv;
    float p = cnt * (1.0f / 65536.0f);
    red[k] = p * logf(p + 1e-10f);
    __syncthreads();
    for (int t = 512; t > 0; t >>= 1) {
        if (k < t) red[k] += red[k + t];
        __syncthreads();
    }
    if (k == 0) {
        out_ent[0] = -red[0];
        out_loss[0] = 0.25f * losssum[0] * (1.0f / 16777216.0f);
    }
}

__global__ __launch_bounds__(256) void k_fin(
    const float* __restrict__ ema_w, const float* __restrict__ cluster,
    float* __restrict__ neww, float* __restrict__ newemb)
{
    int g = blockIdx.x * 256 + threadIdx.x;
    int k = g >> 8;
    float w = ema_w[g] * DECAY_ + OMD_ * neww[g];   // neww currently holds dw
    neww[g] = w;
    newemb[g] = w / cluster[k];
}

extern "C" void kernel_launch(void* const* d_in, const int* in_sizes, int n_in,
                              void* d_out, int out_size, void* d_ws, size_t ws_size,
                              hipStream_t stream)
{
    const float* inp    = (const float*)d_in[0];
    const float* emb    = (const float*)d_in[1];
    const float* ema_cs = (const float*)d_in[2];
    const float* ema_w  = (const float*)d_in[3];

    float* out0        = (float*)d_out;
    float* out_loss    = out0 + OFF_LOSS;
    float* out_ent     = out0 + OFF_ENT;
    float* out_enc     = out0 + OFF_ENC;
    float* out_cluster = out0 + OFF_CLUSTER;
    float* out_neww    = out0 + OFF_NEWW;
    float* out_newemb  = out0 + OFF_NEWEMB;

    unsigned short* ws_xhi  = (unsigned short*)(out0 + OFF_XHI);
    unsigned short* ws_xlo  = (unsigned short*)(out0 + OFF_XLO);
    unsigned short* ws_ehi  = (unsigned short*)(out0 + OFF_EHI);
    unsigned short* ws_elo  = (unsigned short*)(out0 + OFF_ELO);
    int*   ws_sorted  = (int*)(out0 + OFF_SORT2);
    int*   ws_offsets = ws_sorted + 65536;
    int*   ws_cursor  = ws_offsets + 1025;

    int*   ws_idx    = (int*)d_ws;
    int*   ws_counts = ws_idx + 65536;
    int*   ws_flagc  = ws_idx + 66560;
    float* ws_loss   = (float*)(ws_idx + 66561);
    int*   ws_flagl  = ws_idx + 66562;
    float* ws_enorm  = (float*)(ws_idx + 132098);

    float4* encz = (float4*)(out0 + ZTAIL_ABS);

    k_prep_e <<<1024, 64, 0, stream>>>(emb, ws_ehi, ws_elo, ws_enorm);
    k_prep_x <<<2048, 256, 0, stream>>>(inp, ws_xhi, ws_xlo, out_neww, ws_counts);
    k_argmin <<<512, 256, 0, stream>>>(ws_xhi, ws_xlo, ws_ehi, ws_elo, ws_enorm,
                                       ws_idx, ws_flagc, ws_flagl, encz);
    k_rescan <<<256, 256, 0, stream>>>(inp, emb, ws_flagc, ws_flagl, ws_idx);
    k_hist   <<<64, 256, 0, stream>>>(ws_idx, ws_counts);
    k_scan   <<<1, 1024, 0, stream>>>(ws_counts, ws_offsets, ws_cursor);
    k_scatter<<<64, 256, 0, stream>>>(ws_idx, ws_cursor, ws_sorted);
    k_dwg    <<<256, 256, 0, stream>>>(ws_xhi, ws_xlo, ws_sorted, ws_idx, ws_offsets, out_neww);
    k_quant  <<<1024, 256, 0, stream>>>(inp, emb, ws_idx, out0, ws_loss, out_enc);
    k_enc1   <<<64, 256, 0, stream>>>(ws_idx, out_enc);
    k_cluster<<<1, 1024, 0, stream>>>(ema_cs, ws_counts, ws_loss, out_cluster, out_loss, out_ent);
    k_fin    <<<1024, 256, 0, stream>>>(ema_w, out_cluster, out_neww, out_newemb);
}

// Round 8
// 651.634 us; speedup vs baseline: 1.1611x; 1.0163x over previous
//
#include <hip/hip_runtime.h>

// Problem constants
#define B_    64
#define C_    256
#define H_    32
#define W_    32
#define K_    1024
#define D_    256
#define HW_   1024
#define N_    65536
#define NELEM 16777216
#define DECAY_ 0.99f
#define OMD_   0.01f
#define EPS_   1e-5f
#define TAU_   0.05f        // fp64-rescan margin

// d_out float offsets
#define OFF_LOSS    16777216
#define OFF_ENT     16777217
#define OFF_ENC     16777218   // 8B-aligned only
#define OFF_CLUSTER 83886082
#define OFF_NEWW    83887106
#define OFF_NEWEMB  84149250

// Scratch inside the (later overwritten) encodings output region [OFF_ENC, OFF_ENC+67108864):
#define OFF_XHI     (OFF_ENC + 2)              // 16B-aligned; bf16 hi of -2x, [N][D] ushort
#define OFF_XLO     (OFF_XHI + 8388608)
#define OFF_EHI     (OFF_XLO + 8388608)        // bf16 hi of emb, PACKED B-fragment layout (see k_prep_e)
#define OFF_ELO     (OFF_EHI + 131072)
#define OFF_SORT2   (OFF_ELO + 131072)         // sorted[65536] | offsets[1025] | cursor[1024]
// Scratch ends at rel 17106947 (floats rel. to OFF_ENC). First 16B-aligned abs index after:
#define ZTAIL_ABS   33884168                   // = OFF_ENC + 17106950, abs%4==0
#define ZTAIL_F4    12500478                   // float4s in [rel 17106950, rel 67108862)
#define ZHEAD_F4    4276737                    // float4s in [rel 2, rel 17106950)

typedef __attribute__((ext_vector_type(8)))  short short8;
typedef __attribute__((ext_vector_type(16))) float floatx16;

__device__ __forceinline__ unsigned short f2bf(float f) {
    unsigned u = __float_as_uint(f);
    return (unsigned short)((u + 0x7fffu + ((u >> 16) & 1u)) >> 16);
}
__device__ __forceinline__ float bf2f(unsigned short h) {
    return __uint_as_float(((unsigned)h) << 16);
}

// emb -> bf16 hi/lo + enorm.
// PACKED layout for MFMA B-fragments: tile = [K/32][ds=16][h=2][c32=32][j=8] ushorts.
__global__ __launch_bounds__(64) void k_prep_e(const float* __restrict__ emb,
                                               unsigned short* __restrict__ ehi,
                                               unsigned short* __restrict__ elo,
                                               float* __restrict__ enorm) {
    const int k = blockIdx.x;
    const int t = threadIdx.x;       // handles d = 4t .. 4t+3 (same ds, same h)
    float4 v = ((const float4*)(emb + (size_t)k * D_))[t];
    float s = v.x * v.x + v.y * v.y + v.z * v.z + v.w * v.w;
    ushort4 hi, lo;
    {
        float f[4] = {v.x, v.y, v.z, v.w};
        unsigned short h[4], l[4];
        #pragma unroll
        for (int j = 0; j < 4; ++j) {
            h[j] = f2bf(f[j]);
            l[j] = f2bf(f[j] - bf2f(h[j]));
        }
        hi = make_ushort4(h[0], h[1], h[2], h[3]);
        lo = make_ushort4(l[0], l[1], l[2], l[3]);
    }
    size_t o = ((size_t)(k >> 5) << 13) + ((size_t)(t >> 2) << 9)
             + (((size_t)(t >> 1) & 1) << 8) + ((size_t)(k & 31) << 3) + ((t & 1) << 2);
    *(ushort4*)(ehi + o) = hi;
    *(ushort4*)(elo + o) = lo;
    #pragma unroll
    for (int off = 32; off > 0; off >>= 1) s += __shfl_down(s, off);
    if (t == 0) enorm[k] = s;
}

// NCHW -> n-major bf16 hi/lo split of (-2x). Tile 32 d x 256 n per block.
// Folded zero-init: dw[262144], counts/flagcount/losssum, cursor[1024].
__global__ __launch_bounds__(256) void k_prep_x(const float* __restrict__ inp,
                                                unsigned short* __restrict__ xhi,
                                                unsigned short* __restrict__ xlo,
                                                float* __restrict__ dw,
                                                int* __restrict__ small_,
                                                int* __restrict__ cursor) {
    __shared__ float tile[32][257];
    const int tid = threadIdx.x;
    const int bid = blockIdx.x;            // 2048 blocks: b(64) x hwtile(4) x dtile(8)
    if (bid < 1024) {
        int g = bid * 256 + tid;
        dw[g] = 0.0f;                      // 1024*256 == K*D exactly
        if (g < 1026) small_[g] = 0;       // counts[1024] + flagcount + losssum
        if (bid < 4) cursor[bid * 256 + tid] = 0;
    }
    const int dt = bid & 7;
    const int ht = (bid >> 3) & 3;
    const int b = bid >> 5;
    const int d0 = dt * 32;
    const int hw0 = ht * 256;
    const float* src = inp + (size_t)b * (C_ * HW_) + (size_t)d0 * HW_ + hw0;
    #pragma unroll
    for (int i = 0; i < 8; ++i) {
        int idx4 = i * 256 + tid;
        int dl = idx4 >> 6;
        int nl4 = (idx4 & 63) * 4;
        float4 v = *(const float4*)(src + (size_t)dl * HW_ + nl4);
        tile[dl][nl4] = v.x; tile[dl][nl4 + 1] = v.y;
        tile[dl][nl4 + 2] = v.z; tile[dl][nl4 + 3] = v.w;
    }
    __syncthreads();
    const int nbase = b * HW_ + hw0;
    #pragma unroll
    for (int i = 0; i < 4; ++i) {
        int f8 = i * 256 + tid;            // 1024 items of 8 d
        int nl = f8 >> 2;
        int dpos = (f8 & 3) * 8;
        union { unsigned short u[8]; short8 v; } ph, pl;
        #pragma unroll
        for (int j = 0; j < 8; ++j) {
            float f = -2.0f * tile[dpos + j][nl];
            unsigned short h = f2bf(f);
            ph.u[j] = h;
            pl.u[j] = f2bf(f - bf2f(h));
        }
        size_t o = (size_t)(nbase + nl) * D_ + d0 + dpos;
        *(short8*)(xhi + o) = ph.v;
        *(short8*)(xlo + o) = pl.v;
    }
}

// Stage one 16KB+16KB packed B tile into LDS via direct global->LDS DMA.
// 256 threads: 4 iters x 2 arrays = exactly 8 gload_lds instructions per thread.
__device__ __forceinline__ void stage_tile(const unsigned short* __restrict__ gh,
                                           const unsigned short* __restrict__ gl,
                                           unsigned short* sh, unsigned short* sl,
                                           int tid) {
    #pragma unroll
    for (int i = 0; i < 4; ++i) {
        __builtin_amdgcn_global_load_lds(
            (const __attribute__((address_space(1))) unsigned int*)(gh + i * 2048 + tid * 8),
            (__attribute__((address_space(3))) unsigned int*)(sh + i * 2048 + tid * 8),
            16, 0, 0);
        __builtin_amdgcn_global_load_lds(
            (const __attribute__((address_space(1))) unsigned int*)(gl + i * 2048 + tid * 8),
            (__attribute__((address_space(3))) unsigned int*)(sl + i * 2048 + tid * 8),
            16, 0, 0);
    }
}

// MFMA bf16x3 distance argmin on 32x32x16: 32 rows/wave, 32 cols/K-step.
// 256 thr, 2 waves/SIMD, 2 acc chains, LDS dbuf, counted-vmcnt barrier (proven).
// NEW: folded histogram -- after the K-loop the LDS is dead, so the block builds
// a local histogram of its 128 rows and merges nonzero bins into global counts.
__global__ __launch_bounds__(256, 2) void k_argmin(
    const unsigned short* __restrict__ xhi, const unsigned short* __restrict__ xlo,
    const unsigned short* __restrict__ ehi, const unsigned short* __restrict__ elo,
    const float* __restrict__ enorm, int* __restrict__ idx_out,
    int* __restrict__ flagcount, int* __restrict__ flaglist,
    float4* __restrict__ encz, int* __restrict__ counts)
{
    __shared__ unsigned short smem[2][2][8192];   // [buf][hi/lo][16KB] = 64KB
    const int tid = threadIdx.x;
    const int w = tid >> 6;
    const int lane = tid & 63;
    const int c32 = lane & 31;
    const int h = lane >> 5;
    const int r0 = blockIdx.x * 128 + w * 32;
    const int gtid = blockIdx.x * 256 + tid;      // 0..131071
    const float4 z4 = make_float4(0.f, 0.f, 0.f, 0.f);

    // A fragments: row m = lane&31, k = h*8 + j within each 16-chunk
    short8 Ahi[16], Alo[16];
    {
        const unsigned short* pa = xhi + (size_t)(r0 + c32) * D_ + h * 8;
        const unsigned short* pl = xlo + (size_t)(r0 + c32) * D_ + h * 8;
        #pragma unroll
        for (int ds = 0; ds < 16; ++ds) {
            Ahi[ds] = *(const short8*)(pa + ds * 16);
            Alo[ds] = *(const short8*)(pl + ds * 16);
        }
    }

    float b1[16], b2[16];
    int bi[16];
    #pragma unroll
    for (int i = 0; i < 16; ++i) { b1[i] = 3.0e38f; b2[i] = 3.0e38f; bi[i] = 0; }

    // prologue: stage tile 0 into buffer 0 (full drain barrier is fine once)
    stage_tile(ehi, elo, &smem[0][0][0], &smem[0][1][0], tid);
    __syncthreads();

    // per-lane read base within a staged tile: h*256 + c32*8 ushorts
    const int rb = (h << 8) + (c32 << 3);

    int cb = 0;
    for (int ct = 0; ct < 32; ++ct) {
        if (ct + 1 < 32) {
            stage_tile(ehi + (size_t)(ct + 1) * 8192, elo + (size_t)(ct + 1) * 8192,
                       &smem[cb ^ 1][0][0], &smem[cb ^ 1][1][0], tid);
        }
        // pin issue order: all 8 gloads BEFORE the 3 stores (vmcnt retires in order)
        __builtin_amdgcn_sched_barrier(0);
        // background zero-fill of the encodings tail: EXACTLY 3 stores, clamped
        #pragma unroll
        for (int jj = 0; jj < 3; ++jj) {
            int zi = (ct * 3 + jj) * 131072 + gtid;
            zi = (zi < ZTAIL_F4) ? zi : (ZTAIL_F4 - 1);
            encz[zi] = z4;
        }
        const int col = ct * 32 + c32;
        const float en = enorm[col];
        const unsigned short* sbh = &smem[cb][0][rb];
        const unsigned short* sbl = &smem[cb][1][rb];
        floatx16 hh, cr;
        #pragma unroll
        for (int i = 0; i < 16; ++i) { hh[i] = 0.0f; cr[i] = 0.0f; }
        #pragma unroll
        for (int ds = 0; ds < 16; ++ds) {
            short8 bh = *(const short8*)(sbh + ds * 512);
            short8 bl = *(const short8*)(sbl + ds * 512);
            hh = __builtin_amdgcn_mfma_f32_32x32x16_bf16(Ahi[ds], bh, hh, 0, 0, 0);
            cr = __builtin_amdgcn_mfma_f32_32x32x16_bf16(Ahi[ds], bl, cr, 0, 0, 0);
            cr = __builtin_amdgcn_mfma_f32_32x32x16_bf16(Alo[ds], bh, cr, 0, 0, 0);
        }
        #pragma unroll
        for (int r = 0; r < 16; ++r) {
            float v = hh[r] + cr[r] + en;
            bool lt = v < b1[r];
            float nb2 = lt ? b1[r] : fminf(v, b2[r]);   // med3(v, b1, b2)
            b2[r] = nb2;
            b1[r] = lt ? v : b1[r];
            bi[r] = lt ? col : bi[r];
        }
        // counted-vmcnt barrier: staging loads done, newest 3 stores stay in flight
        asm volatile("s_waitcnt vmcnt(3)" ::: "memory");
        __builtin_amdgcn_sched_barrier(0);
        __builtin_amdgcn_s_barrier();
        __builtin_amdgcn_sched_barrier(0);
        cb ^= 1;
    }

    // LDS is dead past the final barrier: reuse first 4KB as a block histogram
    int* histL = (int*)&smem[0][0][0];
    #pragma unroll
    for (int j = 0; j < 4; ++j) histL[tid + j * 256] = 0;
    __syncthreads();

    // reduce each reg's (b1,b2,bi) across the 32 lanes sharing that row (c bits 0..4)
    #pragma unroll
    for (int r = 0; r < 16; ++r) {
        float B1 = b1[r], B2 = b2[r];
        int Bi = bi[r];
        #pragma unroll
        for (int mask = 1; mask <= 16; mask <<= 1) {
            float v1 = __shfl_xor(B1, mask);
            float v2 = __shfl_xor(B2, mask);
            int i1 = __shfl_xor(Bi, mask);
            if (v1 < B1 || (v1 == B1 && i1 < Bi)) {
                B2 = fminf(fminf(B1, B2), v2);
                B1 = v1; Bi = i1;
            } else {
                B2 = fminf(B2, fminf(v1, v2));
            }
        }
        if (c32 == 0) {
            int row = r0 + (r & 3) + 4 * h + 8 * (r >> 2);
            idx_out[row] = Bi;
            atomicAdd(&histL[Bi], 1);
            if (B2 - B1 < TAU_) {
                int p = atomicAdd(flagcount, 1);
                flaglist[p] = row;
            }
        }
    }
    __syncthreads();
    #pragma unroll
    for (int j = 0; j < 4; ++j) {
        int v = histL[tid + j * 256];
        if (v) atomicAdd(&counts[tid + j * 256], v);
    }
}

// Exact fp64 rescan of flagged (near-tie) rows; incrementally fixes counts.
__global__ __launch_bounds__(256) void k_rescan(
    const float* __restrict__ inp, const float* __restrict__ emb,
    const int* __restrict__ flagcount, const int* __restrict__ flaglist,
    int* __restrict__ idx_out, int* __restrict__ counts)
{
    __shared__ double xd[256];
    __shared__ double sv[256];
    __shared__ int si[256];
    const int tid = threadIdx.x;
    const int nflag = *flagcount;
    for (int f = blockIdx.x; f < nflag; f += gridDim.x) {
        int n = flaglist[f];
        int b = n >> 10, nn = n & 1023;
        xd[tid] = (double)inp[(size_t)b * (C_ * HW_) + (size_t)tid * HW_ + nn];
        __syncthreads();
        double bv = 1e300; int bi = 0;
        for (int k = tid; k < K_; k += 256) {
            const float* ep = emb + (size_t)k * D_;
            double dot = 0.0, en = 0.0;
            for (int d = 0; d < D_; ++d) {
                double e = (double)ep[d];
                dot = fma(xd[d], e, dot);
                en  = fma(e, e, en);
            }
            double v = en - 2.0 * dot;
            if (v < bv) { bv = v; bi = k; }
        }
        sv[tid] = bv; si[tid] = bi;
        __syncthreads();
        for (int s = 128; s > 0; s >>= 1) {
            if (tid < s) {
                if (sv[tid + s] < sv[tid] || (sv[tid + s] == sv[tid] && si[tid + s] < si[tid])) {
                    sv[tid] = sv[tid + s]; si[tid] = si[tid + s];
                }
            }
            __syncthreads();
        }
        if (tid == 0) {
            int old = idx_out[n];
            int nw = si[0];
            if (nw != old) {
                idx_out[n] = nw;
                atomicAdd(&counts[old], -1);
                atomicAdd(&counts[nw], 1);
            }
        }
        __syncthreads();
    }
}

// Block-aggregated scatter with LOCAL exclusive scan of final counts (k_scan folded).
// cursor pre-zeroed in k_prep_x; p = excl[k] + global claim + intra-block rank.
// Block 0 publishes offsets[0..1024] for k_dwg.
__global__ __launch_bounds__(256) void k_scatter(const int* __restrict__ idx,
                                                 const int* __restrict__ counts,
                                                 int* __restrict__ cursor,
                                                 int* __restrict__ sorted,
                                                 int* __restrict__ offsets) {
    __shared__ int sc[1024];
    __shared__ int hc[1024];
    __shared__ int hb[1024];
    const int tid = threadIdx.x;
    const int base = blockIdx.x * 1024;
    int creg[4];
    #pragma unroll
    for (int j = 0; j < 4; ++j) {
        int k = tid + j * 256;
        creg[j] = counts[k];
        sc[k] = creg[j];
        hc[k] = 0;
    }
    __syncthreads();
    for (int off = 1; off < 1024; off <<= 1) {
        int t0[4];
        #pragma unroll
        for (int j = 0; j < 4; ++j) {
            int k = tid + j * 256;
            t0[j] = (k >= off) ? sc[k - off] : 0;
        }
        __syncthreads();
        #pragma unroll
        for (int j = 0; j < 4; ++j) sc[tid + j * 256] += t0[j];
        __syncthreads();
    }
    // inclusive -> exclusive (own entries only)
    #pragma unroll
    for (int j = 0; j < 4; ++j) {
        int k = tid + j * 256;
        sc[k] -= creg[j];
    }
    __syncthreads();
    if (blockIdx.x == 0) {
        #pragma unroll
        for (int j = 0; j < 4; ++j) {
            int k = tid + j * 256;
            offsets[k] = sc[k];
            if (k == 1023) offsets[1024] = sc[1023] + creg[j];
        }
    }
    int myk[4], myn[4];
    #pragma unroll
    for (int j = 0; j < 4; ++j) {
        int n = base + j * 256 + tid;
        myn[j] = n;
        myk[j] = idx[n];
        atomicAdd(&hc[myk[j]], 1);
    }
    __syncthreads();
    #pragma unroll
    for (int j = 0; j < 4; ++j) {
        int kk = tid + j * 256;
        int c = hc[kk];
        hb[kk] = c ? atomicAdd(&cursor[kk], c) : 0;
    }
    __syncthreads();
    #pragma unroll
    for (int j = 0; j < 4; ++j) hc[tid + j * 256] = 0;
    __syncthreads();
    #pragma unroll
    for (int j = 0; j < 4; ++j) {
        int p = sc[myk[j]] + hb[myk[j]] + atomicAdd(&hc[myk[j]], 1);
        sorted[p] = myn[j];
    }
}

// Balanced segmented dw reduction reading xhi/xlo (x = -0.5*(hi+lo), exact to 2^-18).
__global__ __launch_bounds__(256) void k_dwg(const unsigned short* __restrict__ xhi,
                                             const unsigned short* __restrict__ xlo,
                                             const int* __restrict__ sorted,
                                             const int* __restrict__ idx,
                                             const int* __restrict__ offsets,
                                             float* __restrict__ dw) {
    const int lane = threadIdx.x & 63;
    const int wid = threadIdx.x >> 6;
    const int wbase = (blockIdx.x * 4 + wid) * 64;

    int myn = sorted[wbase + lane];
    int myk = idx[myn];

    float4 acc = make_float4(0.f, 0.f, 0.f, 0.f);
    int cur = __shfl(myk, 0);

    #pragma unroll 8
    for (int i = 0; i < 64; ++i) {
        int n = __shfl(myn, i);
        int k = __shfl(myk, i);
        if (k != cur) {
            bool full = (offsets[cur] >= wbase) && (offsets[cur + 1] <= wbase + 64);
            float* dwk = dw + (size_t)cur * D_ + lane * 4;
            if (full) {
                ((float2*)dwk)[0] = make_float2(-0.5f * acc.x, -0.5f * acc.y);
                ((float2*)dwk)[1] = make_float2(-0.5f * acc.z, -0.5f * acc.w);
            } else {
                atomicAdd(dwk + 0, -0.5f * acc.x);
                atomicAdd(dwk + 1, -0.5f * acc.y);
                atomicAdd(dwk + 2, -0.5f * acc.z);
                atomicAdd(dwk + 3, -0.5f * acc.w);
            }
            acc = make_float4(0.f, 0.f, 0.f, 0.f);
            cur = k;
        }
        size_t o = (size_t)n * D_ + lane * 4;
        ushort4 hx = *(const ushort4*)(xhi + o);
        ushort4 lx = *(const ushort4*)(xlo + o);
        acc.x += bf2f(hx.x) + bf2f(lx.x);
        acc.y += bf2f(hx.y) + bf2f(lx.y);
        acc.z += bf2f(hx.z) + bf2f(lx.z);
        acc.w += bf2f(hx.w) + bf2f(lx.w);
    }
    {
        bool full = (offsets[cur] >= wbase) && (offsets[cur + 1] <= wbase + 64);
        float* dwk = dw + (size_t)cur * D_ + lane * 4;
        if (full) {
            ((float2*)dwk)[0] = make_float2(-0.5f * acc.x, -0.5f * acc.y);
            ((float2*)dwk)[1] = make_float2(-0.5f * acc.z, -0.5f * acc.w);
        } else {
            atomicAdd(dwk + 0, -0.5f * acc.x);
            atomicAdd(dwk + 1, -0.5f * acc.y);
            atomicAdd(dwk + 2, -0.5f * acc.z);
            atomicAdd(dwk + 3, -0.5f * acc.w);
        }
    }
}

// Quantize + loss (LDS-transposed embedding gather) + folded head-zero of the
// scratch region. Block = (batch b, 64-wide hw tile).
__global__ __launch_bounds__(256) void k_quant(
    const float* __restrict__ inp, const float* __restrict__ emb,
    const int* __restrict__ idx, float* __restrict__ outp, float* __restrict__ losssum,
    float* __restrict__ enc)
{
    __shared__ float qt[64][260];      // [n_local][c], pad 260 -> conflict-free b128 writes
    __shared__ int karr[64];
    __shared__ float red[256];
    const int tid = threadIdx.x;
    const int bid = blockIdx.x;        // 1024 blocks: b(64) x hwtile(16)
    const int b = bid >> 4;
    const int ht = bid & 15;
    const int base_n = b * HW_ + ht * 64;

    // folded head-zero: [OFF_ENC+2, OFF_ENC+17106950) as float4, fire-and-forget
    {
        const float4 z4 = make_float4(0.f, 0.f, 0.f, 0.f);
        float4* pz = (float4*)(enc + 2);
        int t = bid * 256 + tid;       // 262144 threads
        #pragma unroll
        for (int it = 0; it < 17; ++it) {
            int i = it * 262144 + t;
            if (i < ZHEAD_F4) pz[i] = z4;
        }
        if (t == 0) { enc[0] = 0.f; enc[1] = 0.f; enc[67108862] = 0.f; enc[67108863] = 0.f; }
    }

    if (tid < 64) karr[tid] = idx[base_n + tid];
    __syncthreads();

    // gather 64 emb rows into LDS, coalesced: 16 float4 per thread, 64 threads/row
    #pragma unroll
    for (int it = 0; it < 16; ++it) {
        int f = it * 256 + tid;        // 0..4095
        int r = f >> 6;                // row 0..63
        int c4 = (f & 63) << 2;        // col 0,4,...,252
        float4 v = ((const float4*)emb)[karr[r] * 64 + (c4 >> 2)];
        *(float4*)(&qt[r][c4]) = v;    // row-contiguous across the wave: conflict-free
    }
    __syncthreads();

    // emit: thread handles (c, 4 consecutive hw): coalesced 256B chunks
    float s = 0.0f;
    #pragma unroll
    for (int it = 0; it < 16; ++it) {
        int f = it * 256 + tid;        // 0..4095
        int c = f >> 4;                // 0..255
        int hl = (f & 15) << 2;        // hw_local 0,4,...,60
        int g = b * 65536 + c * 256 + ht * 16 + (hl >> 2);   // float4 index
        float4 x = ((const float4*)inp)[g];
        float q0 = qt[hl + 0][c];
        float q1 = qt[hl + 1][c];
        float q2 = qt[hl + 2][c];
        float q3 = qt[hl + 3][c];
        float d0 = q0 - x.x, d1 = q1 - x.y, d2 = q2 - x.z, d3 = q3 - x.w;
        ((float4*)outp)[g] = make_float4(x.x + d0, x.y + d1, x.z + d2, x.w + d3);
        s += d0 * d0 + d1 * d1 + d2 * d2 + d3 * d3;
    }
    red[tid] = s;
    __syncthreads();
    for (int t = 128; t > 0; t >>= 1) {
        if (tid < t) red[tid] += red[tid + t];
        __syncthreads();
    }
    if (tid == 0) atomicAdd(losssum, red[0]);
}

// Final fused kernel: cluster EMA (redundant per-block nsum reduce of the 4KB
// counts array), ema_w/new_embedding, loss+entropy (block 0), and the one-hot
// writes (64 rows per block; safe after k_quant's zero-fill by stream order).
__global__ __launch_bounds__(256) void k_fin(
    const float* __restrict__ ema_cs, const int* __restrict__ counts,
    const float* __restrict__ losssum, const float* __restrict__ ema_w,
    const int* __restrict__ idx,
    float* __restrict__ neww, float* __restrict__ newemb,
    float* __restrict__ out_cluster, float* __restrict__ out_loss,
    float* __restrict__ out_ent, float* __restrict__ enc)
{
    __shared__ float sraw[1024];
    __shared__ float red[256];
    __shared__ float sclv;
    const int tid = threadIdx.x;
    const int bid = blockIdx.x;        // 1024 blocks; block bid owns k = bid
    float part = 0.f;
    float ent = 0.f;
    #pragma unroll
    for (int j = 0; j < 4; ++j) {
        int k = tid + j * 256;
        float cnt = (float)counts[k];
        float raw = ema_cs[k] * DECAY_ + OMD_ * cnt;
        sraw[k] = raw;
        part += raw;
        float p = cnt * (1.0f / 65536.0f);
        ent += p * logf(p + 1e-10f);
    }
    red[tid] = part;
    __syncthreads();
    for (int t = 128; t > 0; t >>= 1) {
        if (tid < t) red[tid] += red[tid + t];
        __syncthreads();
    }
    float nsum = red[0];
    __syncthreads();
    red[tid] = ent;
    __syncthreads();
    for (int t = 128; t > 0; t >>= 1) {
        if (tid < t) red[tid] += red[tid + t];
        __syncthreads();
    }
    if (tid == 0) {
        float clv = (sraw[bid] + EPS_) / (nsum + 1024.0f * EPS_) * nsum;
        sclv = clv;
        out_cluster[bid] = clv;
        if (bid == 0) {
            out_ent[0] = -red[0];
            out_loss[0] = 0.25f * losssum[0] * (1.0f / 16777216.0f);
        }
    }
    __syncthreads();
    float clv = sclv;
    int g = bid * 256 + tid;
    float w = ema_w[g] * DECAY_ + OMD_ * neww[g];   // neww currently holds dw
    neww[g] = w;
    newemb[g] = w / clv;
    // folded enc1: one-hot writes, 64 rows per block
    if (tid < 64) {
        int n = bid * 64 + tid;
        enc[(size_t)n * 1024 + idx[n]] = 1.0f;
    }
}

extern "C" void kernel_launch(void* const* d_in, const int* in_sizes, int n_in,
                              void* d_out, int out_size, void* d_ws, size_t ws_size,
                              hipStream_t stream)
{
    const float* inp    = (const float*)d_in[0];
    const float* emb    = (const float*)d_in[1];
    const float* ema_cs = (const float*)d_in[2];
    const float* ema_w  = (const float*)d_in[3];

    float* out0        = (float*)d_out;
    float* out_loss    = out0 + OFF_LOSS;
    float* out_ent     = out0 + OFF_ENT;
    float* out_enc     = out0 + OFF_ENC;
    float* out_cluster = out0 + OFF_CLUSTER;
    float* out_neww    = out0 + OFF_NEWW;
    float* out_newemb  = out0 + OFF_NEWEMB;

    unsigned short* ws_xhi  = (unsigned short*)(out0 + OFF_XHI);
    unsigned short* ws_xlo  = (unsigned short*)(out0 + OFF_XLO);
    unsigned short* ws_ehi  = (unsigned short*)(out0 + OFF_EHI);
    unsigned short* ws_elo  = (unsigned short*)(out0 + OFF_ELO);
    int*   ws_sorted  = (int*)(out0 + OFF_SORT2);
    int*   ws_offsets = ws_sorted + 65536;
    int*   ws_cursor  = ws_offsets + 1025;

    int*   ws_idx    = (int*)d_ws;
    int*   ws_counts = ws_idx + 65536;
    int*   ws_flagc  = ws_idx + 66560;
    float* ws_loss   = (float*)(ws_idx + 66561);
    int*   ws_flagl  = ws_idx + 66562;
    float* ws_enorm  = (float*)(ws_idx + 132098);

    float4* encz = (float4*)(out0 + ZTAIL_ABS);

    k_prep_e <<<1024, 64, 0, stream>>>(emb, ws_ehi, ws_elo, ws_enorm);
    k_prep_x <<<2048, 256, 0, stream>>>(inp, ws_xhi, ws_xlo, out_neww, ws_counts, ws_cursor);
    k_argmin <<<512, 256, 0, stream>>>(ws_xhi, ws_xlo, ws_ehi, ws_elo, ws_enorm,
                                       ws_idx, ws_flagc, ws_flagl, encz, ws_counts);
    k_rescan <<<256, 256, 0, stream>>>(inp, emb, ws_flagc, ws_flagl, ws_idx, ws_counts);
    k_scatter<<<64, 256, 0, stream>>>(ws_idx, ws_counts, ws_cursor, ws_sorted, ws_offsets);
    k_dwg    <<<256, 256, 0, stream>>>(ws_xhi, ws_xlo, ws_sorted, ws_idx, ws_offsets, out_neww);
    k_quant  <<<1024, 256, 0, stream>>>(inp, emb, ws_idx, out0, ws_loss, out_enc);
    k_fin    <<<1024, 256, 0, stream>>>(ema_cs, ws_counts, ws_loss, ema_w, ws_idx,
                                        out_neww, out_newemb, out_cluster, out_loss,
                                        out_ent, out_enc);
}

// Round 9
// 604.681 us; speedup vs baseline: 1.2513x; 1.0776x over previous
//
#include <hip/hip_runtime.h>

// Problem constants
#define B_    64
#define C_    256
#define H_    32
#define W_    32
#define K_    1024
#define D_    256
#define HW_   1024
#define N_    65536
#define NELEM 16777216
#define DECAY_ 0.99f
#define OMD_   0.01f
#define EPS_   1e-5f
#define TAU_   0.05f        // fp64-rescan margin

// d_out float offsets
#define OFF_LOSS    16777216
#define OFF_ENT     16777217
#define OFF_ENC     16777218   // 8B-aligned only
#define OFF_CLUSTER 83886082
#define OFF_NEWW    83887106
#define OFF_NEWEMB  84149250

// Scratch inside the (later overwritten) encodings output region [OFF_ENC, OFF_ENC+67108864):
// int8 hi/lo planes of q = clamp(round(-4096*x)) (i.e. -2x at scale 2^11), [N][D] bytes each,
// and packed int8 B-fragment tiles of e at the same scale.
#define OFF_XH      (OFF_ENC + 2)              // 16MB plane (as floats: 4194304)
#define OFF_XL      (OFF_XH + 4194304)
#define OFF_EH      (OFF_XL + 4194304)         // packed B tiles, 256KB (65536 floats)
#define OFF_EL      (OFF_EH + 65536)
#define OFF_SORT2   (OFF_EL + 65536)           // sorted[65536] | offsets[1025] | cursor[1024]
// Scratch ends at rel 8587267 floats. Tail/head zero regions (16B-aligned float4):
#define ZTAIL_ABS   25364488                   // abs float idx, %4==0
#define ZTAIL_F4    14630398                   // float4s in tail
#define ZHEAD_F4    2146817                    // float4s in [rel 2, tail start)

typedef __attribute__((ext_vector_type(8)))  short short8;
typedef __attribute__((ext_vector_type(4)))  int   intx4;
typedef __attribute__((ext_vector_type(16))) int   intx16;

__global__ __launch_bounds__(64) void k_prep_e(const float* __restrict__ emb,
                                               signed char* __restrict__ eh,
                                               signed char* __restrict__ el,
                                               float* __restrict__ enorm) {
    // Packed B layout for mfma_i32_32x32x32_i8: tile(k>>5) of 8192 bytes =
    // [ds=8][h=2][c32=32][j=16]; element (k,d): ds=d>>5, h=(d>>4)&1, c32=k&31, j=d&15.
    const int k = blockIdx.x;
    const int t = threadIdx.x;       // handles d = 4t .. 4t+3 (same ds, same h)
    float4 v = ((const float4*)(emb + (size_t)k * D_))[t];
    float s = v.x * v.x + v.y * v.y + v.z * v.z + v.w * v.w;
    signed char hq[4], lq[4];
    {
        float f[4] = {v.x, v.y, v.z, v.w};
        #pragma unroll
        for (int j = 0; j < 4; ++j) {
            int q = (int)rintf(f[j] * 2048.0f);
            q = q < -32640 ? -32640 : (q > 32639 ? 32639 : q);
            int hh = (q + 128) >> 8;
            hq[j] = (signed char)hh;
            lq[j] = (signed char)(q - (hh << 8));
        }
    }
    size_t o = (size_t)(k >> 5) * 8192 + (size_t)(t >> 3) * 1024
             + (size_t)((t >> 2) & 1) * 512 + (size_t)(k & 31) * 16 + (t & 3) * 4;
    *(char4*)(eh + o) = make_char4(hq[0], hq[1], hq[2], hq[3]);
    *(char4*)(el + o) = make_char4(lq[0], lq[1], lq[2], lq[3]);
    #pragma unroll
    for (int off = 32; off > 0; off >>= 1) s += __shfl_down(s, off);
    if (t == 0) enorm[k] = s;      // exact fp32 norm of ORIGINAL e
}

// NCHW -> n-major int8 hi/lo split of q = round(-4096*x). Tile 32 d x 256 n per block.
// Folded zero-init: dw[262144], counts/flagcount/losssum, cursor[1024].
__global__ __launch_bounds__(256) void k_prep_x(const float* __restrict__ inp,
                                                signed char* __restrict__ xh,
                                                signed char* __restrict__ xl,
                                                float* __restrict__ dw,
                                                int* __restrict__ small_,
                                                int* __restrict__ cursor) {
    __shared__ float tile[32][257];
    const int tid = threadIdx.x;
    const int bid = blockIdx.x;            // 2048 blocks: b(64) x hwtile(4) x dtile(8)
    if (bid < 1024) {
        int g = bid * 256 + tid;
        dw[g] = 0.0f;
        if (g < 1026) small_[g] = 0;
        if (bid < 4) cursor[bid * 256 + tid] = 0;
    }
    const int dt = bid & 7;
    const int ht = (bid >> 3) & 3;
    const int b = bid >> 5;
    const int d0 = dt * 32;
    const int hw0 = ht * 256;
    const float* src = inp + (size_t)b * (C_ * HW_) + (size_t)d0 * HW_ + hw0;
    #pragma unroll
    for (int i = 0; i < 8; ++i) {
        int idx4 = i * 256 + tid;
        int dl = idx4 >> 6;
        int nl4 = (idx4 & 63) * 4;
        float4 v = *(const float4*)(src + (size_t)dl * HW_ + nl4);
        tile[dl][nl4] = v.x; tile[dl][nl4 + 1] = v.y;
        tile[dl][nl4 + 2] = v.z; tile[dl][nl4 + 3] = v.w;
    }
    __syncthreads();
    const int nbase = b * HW_ + hw0;
    #pragma unroll
    for (int i = 0; i < 4; ++i) {
        int f8 = i * 256 + tid;            // 1024 items of 8 d
        int nl = f8 >> 2;
        int dpos = (f8 & 3) * 8;
        union { signed char c[8]; long long v; } ph, pl;
        #pragma unroll
        for (int j = 0; j < 8; ++j) {
            int q = (int)rintf(-4096.0f * tile[dpos + j][nl]);
            q = q < -32640 ? -32640 : (q > 32639 ? 32639 : q);
            int hh = (q + 128) >> 8;
            ph.c[j] = (signed char)hh;
            pl.c[j] = (signed char)(q - (hh << 8));
        }
        size_t o = (size_t)(nbase + nl) * D_ + d0 + dpos;
        *(long long*)(xh + o) = ph.v;
        *(long long*)(xl + o) = pl.v;
    }
}

// Stage one 8KB+8KB packed int8 B tile into LDS: 256 threads x 2 iters x 2 arrays
// = exactly 4 gload_lds instructions per thread.
__device__ __forceinline__ void stage_tile8(const signed char* __restrict__ gh,
                                            const signed char* __restrict__ gl,
                                            signed char* sh, signed char* sl,
                                            int tid) {
    #pragma unroll
    for (int i = 0; i < 2; ++i) {
        __builtin_amdgcn_global_load_lds(
            (const __attribute__((address_space(1))) unsigned int*)(gh + i * 4096 + tid * 16),
            (__attribute__((address_space(3))) unsigned int*)(sh + i * 4096 + tid * 16),
            16, 0, 0);
        __builtin_amdgcn_global_load_lds(
            (const __attribute__((address_space(1))) unsigned int*)(gl + i * 4096 + tid * 16),
            (__attribute__((address_space(3))) unsigned int*)(sl + i * 4096 + tid * 16),
            16, 0, 0);
    }
}

// i8-MFMA distance argmin (mfma_i32_32x32x32_i8, K=32): 32 rows/wave, 32 cols/K-step.
// q_x = -4096x, q_e = 2048e as int16 = 256*hi + lo (int8 planes). Four i32 partial
// dots (hh, hl, lh, ll) are EXACT; combine in fp32: dot = (hh*65536 + (hl+lh)*256
// + ll) * 2^-22. LDS B-traffic halves vs bf16x3 (16KB/wave/step), MFMA 48->32.
// Counted-vmcnt barrier: 4 gloads then 4 clamped zero-stores per step -> vmcnt(4).
__global__ __launch_bounds__(256, 2) void k_argmin(
    const signed char* __restrict__ xh, const signed char* __restrict__ xl,
    const signed char* __restrict__ eh, const signed char* __restrict__ el,
    const float* __restrict__ enorm, int* __restrict__ idx_out,
    int* __restrict__ flagcount, int* __restrict__ flaglist,
    float4* __restrict__ encz, int* __restrict__ counts)
{
    __shared__ __align__(16) signed char smem[2][2][8192];   // 32KB
    const int tid = threadIdx.x;
    const int w = tid >> 6;
    const int lane = tid & 63;
    const int c32 = lane & 31;
    const int h = lane >> 5;
    const int r0 = blockIdx.x * 128 + w * 32;
    const int gtid = blockIdx.x * 256 + tid;      // 0..131071
    const float4 z4 = make_float4(0.f, 0.f, 0.f, 0.f);

    // A fragments: row = lane&31, k = h*16 + j (16 consecutive bytes per ds-chunk)
    intx4 Ah[8], Al[8];
    {
        const signed char* pa = xh + (size_t)(r0 + c32) * D_ + h * 16;
        const signed char* pl = xl + (size_t)(r0 + c32) * D_ + h * 16;
        #pragma unroll
        for (int ds = 0; ds < 8; ++ds) {
            Ah[ds] = *(const intx4*)(pa + ds * 32);
            Al[ds] = *(const intx4*)(pl + ds * 32);
        }
    }

    float b1[16], b2[16];
    int bi[16];
    #pragma unroll
    for (int i = 0; i < 16; ++i) { b1[i] = 3.0e38f; b2[i] = 3.0e38f; bi[i] = 0; }

    // prologue: stage tile 0 into buffer 0
    stage_tile8(eh, el, &smem[0][0][0], &smem[0][1][0], tid);
    __syncthreads();

    // per-lane B read base: col = lane&31 -> h*512 + c32*16 bytes
    const int rb = (h << 9) + (c32 << 4);

    int cb = 0;
    for (int ct = 0; ct < 32; ++ct) {
        if (ct + 1 < 32) {
            stage_tile8(eh + (size_t)(ct + 1) * 8192, el + (size_t)(ct + 1) * 8192,
                        &smem[cb ^ 1][0][0], &smem[cb ^ 1][1][0], tid);
        }
        // pin issue order: all 4 gloads BEFORE the 4 stores (vmcnt retires in order)
        __builtin_amdgcn_sched_barrier(0);
        // background zero-fill of the encodings tail: EXACTLY 4 stores, clamped
        // (131072 thr x 4 x 32 = 16.78M >= ZTAIL_F4; duplicate zeros idempotent)
        #pragma unroll
        for (int jj = 0; jj < 4; ++jj) {
            int zi = (ct * 4 + jj) * 131072 + gtid;
            zi = (zi < ZTAIL_F4) ? zi : (ZTAIL_F4 - 1);
            encz[zi] = z4;
        }
        const int col = ct * 32 + c32;
        const float en = enorm[col];
        const signed char* sbh = &smem[cb][0][rb];
        const signed char* sbl = &smem[cb][1][rb];
        intx16 hh, m1, m2, ll;
        #pragma unroll
        for (int i = 0; i < 16; ++i) { hh[i] = 0; m1[i] = 0; m2[i] = 0; ll[i] = 0; }
        #pragma unroll
        for (int ds = 0; ds < 8; ++ds) {
            intx4 bh = *(const intx4*)(sbh + ds * 1024);
            intx4 bl = *(const intx4*)(sbl + ds * 1024);
            hh = __builtin_amdgcn_mfma_i32_32x32x32_i8(Ah[ds], bh, hh, 0, 0, 0);
            m1 = __builtin_amdgcn_mfma_i32_32x32x32_i8(Ah[ds], bl, m1, 0, 0, 0);
            m2 = __builtin_amdgcn_mfma_i32_32x32x32_i8(Al[ds], bh, m2, 0, 0, 0);
            ll = __builtin_amdgcn_mfma_i32_32x32x32_i8(Al[ds], bl, ll, 0, 0, 0);
        }
        #pragma unroll
        for (int r = 0; r < 16; ++r) {
            float dot = (float)hh[r] * 65536.0f + (float)(m1[r] + m2[r]) * 256.0f
                      + (float)ll[r];
            float v = en + dot * 2.384185791015625e-07f;   // * 2^-22
            bool lt = v < b1[r];
            float nb2 = lt ? b1[r] : fminf(v, b2[r]);
            b2[r] = nb2;
            b1[r] = lt ? v : b1[r];
            bi[r] = lt ? col : bi[r];
        }
        // counted-vmcnt barrier: staging loads done, newest 4 stores stay in flight
        asm volatile("s_waitcnt vmcnt(4)" ::: "memory");
        __builtin_amdgcn_sched_barrier(0);
        __builtin_amdgcn_s_barrier();
        __builtin_amdgcn_sched_barrier(0);
        cb ^= 1;
    }

    // LDS is dead: reuse first 4KB as the block histogram
    int* histL = (int*)&smem[0][0][0];
    #pragma unroll
    for (int j = 0; j < 4; ++j) histL[tid + j * 256] = 0;
    __syncthreads();

    #pragma unroll
    for (int r = 0; r < 16; ++r) {
        float B1 = b1[r], B2 = b2[r];
        int Bi = bi[r];
        #pragma unroll
        for (int mask = 1; mask <= 16; mask <<= 1) {
            float v1 = __shfl_xor(B1, mask);
            float v2 = __shfl_xor(B2, mask);
            int i1 = __shfl_xor(Bi, mask);
            if (v1 < B1 || (v1 == B1 && i1 < Bi)) {
                B2 = fminf(fminf(B1, B2), v2);
                B1 = v1; Bi = i1;
            } else {
                B2 = fminf(B2, fminf(v1, v2));
            }
        }
        if (c32 == 0) {
            int row = r0 + (r & 3) + 4 * h + 8 * (r >> 2);
            idx_out[row] = Bi;
            atomicAdd(&histL[Bi], 1);
            if (B2 - B1 < TAU_) {
                int p = atomicAdd(flagcount, 1);
                flaglist[p] = row;
            }
        }
    }
    __syncthreads();
    #pragma unroll
    for (int j = 0; j < 4; ++j) {
        int v = histL[tid + j * 256];
        if (v) atomicAdd(&counts[tid + j * 256], v);
    }
}

// Exact fp64 rescan of flagged (near-tie) rows; incrementally fixes counts.
__global__ __launch_bounds__(256) void k_rescan(
    const float* __restrict__ inp, const float* __restrict__ emb,
    const int* __restrict__ flagcount, const int* __restrict__ flaglist,
    int* __restrict__ idx_out, int* __restrict__ counts)
{
    __shared__ double xd[256];
    __shared__ double sv[256];
    __shared__ int si[256];
    const int tid = threadIdx.x;
    const int nflag = *flagcount;
    for (int f = blockIdx.x; f < nflag; f += gridDim.x) {
        int n = flaglist[f];
        int b = n >> 10, nn = n & 1023;
        xd[tid] = (double)inp[(size_t)b * (C_ * HW_) + (size_t)tid * HW_ + nn];
        __syncthreads();
        double bv = 1e300; int bi = 0;
        for (int k = tid; k < K_; k += 256) {
            const float* ep = emb + (size_t)k * D_;
            double dot = 0.0, en = 0.0;
            for (int d = 0; d < D_; ++d) {
                double e = (double)ep[d];
                dot = fma(xd[d], e, dot);
                en  = fma(e, e, en);
            }
            double v = en - 2.0 * dot;
            if (v < bv) { bv = v; bi = k; }
        }
        sv[tid] = bv; si[tid] = bi;
        __syncthreads();
        for (int s = 128; s > 0; s >>= 1) {
            if (tid < s) {
                if (sv[tid + s] < sv[tid] || (sv[tid + s] == sv[tid] && si[tid + s] < si[tid])) {
                    sv[tid] = sv[tid + s]; si[tid] = si[tid + s];
                }
            }
            __syncthreads();
        }
        if (tid == 0) {
            int old = idx_out[n];
            int nw = si[0];
            if (nw != old) {
                idx_out[n] = nw;
                atomicAdd(&counts[old], -1);
                atomicAdd(&counts[nw], 1);
            }
        }
        __syncthreads();
    }
}

// Block-aggregated scatter with local exclusive scan of final counts.
__global__ __launch_bounds__(256) void k_scatter(const int* __restrict__ idx,
                                                 const int* __restrict__ counts,
                                                 int* __restrict__ cursor,
                                                 int* __restrict__ sorted,
                                                 int* __restrict__ offsets) {
    __shared__ int sc[1024];
    __shared__ int hc[1024];
    __shared__ int hb[1024];
    const int tid = threadIdx.x;
    const int base = blockIdx.x * 1024;
    int creg[4];
    #pragma unroll
    for (int j = 0; j < 4; ++j) {
        int k = tid + j * 256;
        creg[j] = counts[k];
        sc[k] = creg[j];
        hc[k] = 0;
    }
    __syncthreads();
    for (int off = 1; off < 1024; off <<= 1) {
        int t0[4];
        #pragma unroll
        for (int j = 0; j < 4; ++j) {
            int k = tid + j * 256;
            t0[j] = (k >= off) ? sc[k - off] : 0;
        }
        __syncthreads();
        #pragma unroll
        for (int j = 0; j < 4; ++j) sc[tid + j * 256] += t0[j];
        __syncthreads();
    }
    #pragma unroll
    for (int j = 0; j < 4; ++j) {
        int k = tid + j * 256;
        sc[k] -= creg[j];
    }
    __syncthreads();
    if (blockIdx.x == 0) {
        #pragma unroll
        for (int j = 0; j < 4; ++j) {
            int k = tid + j * 256;
            offsets[k] = sc[k];
            if (k == 1023) offsets[1024] = sc[1023] + creg[j];
        }
    }
    int myk[4], myn[4];
    #pragma unroll
    for (int j = 0; j < 4; ++j) {
        int n = base + j * 256 + tid;
        myn[j] = n;
        myk[j] = idx[n];
        atomicAdd(&hc[myk[j]], 1);
    }
    __syncthreads();
    #pragma unroll
    for (int j = 0; j < 4; ++j) {
        int kk = tid + j * 256;
        int c = hc[kk];
        hb[kk] = c ? atomicAdd(&cursor[kk], c) : 0;
    }
    __syncthreads();
    #pragma unroll
    for (int j = 0; j < 4; ++j) hc[tid + j * 256] = 0;
    __syncthreads();
    #pragma unroll
    for (int j = 0; j < 4; ++j) {
        int p = sc[myk[j]] + hb[myk[j]] + atomicAdd(&hc[myk[j]], 1);
        sorted[p] = myn[j];
    }
}

// Balanced segmented dw reduction from int8 planes: EXACT int32 accumulation of
// q = 256*xh + xl (= -4096x); dw = -sum(q)/4096 = sum(x).
__global__ __launch_bounds__(256) void k_dwg(const signed char* __restrict__ xh,
                                             const signed char* __restrict__ xl,
                                             const int* __restrict__ sorted,
                                             const int* __restrict__ idx,
                                             const int* __restrict__ offsets,
                                             float* __restrict__ dw) {
    const int lane = threadIdx.x & 63;
    const int wid = threadIdx.x >> 6;
    const int wbase = (blockIdx.x * 4 + wid) * 64;

    int myn = sorted[wbase + lane];
    int myk = idx[myn];

    int4 acc = make_int4(0, 0, 0, 0);
    int cur = __shfl(myk, 0);
    const float sc = -1.0f / 4096.0f;

    #pragma unroll 8
    for (int i = 0; i < 64; ++i) {
        int n = __shfl(myn, i);
        int k = __shfl(myk, i);
        if (k != cur) {
            bool full = (offsets[cur] >= wbase) && (offsets[cur + 1] <= wbase + 64);
            float* dwk = dw + (size_t)cur * D_ + lane * 4;
            if (full) {
                ((float2*)dwk)[0] = make_float2(sc * acc.x, sc * acc.y);
                ((float2*)dwk)[1] = make_float2(sc * acc.z, sc * acc.w);
            } else {
                atomicAdd(dwk + 0, sc * acc.x);
                atomicAdd(dwk + 1, sc * acc.y);
                atomicAdd(dwk + 2, sc * acc.z);
                atomicAdd(dwk + 3, sc * acc.w);
            }
            acc = make_int4(0, 0, 0, 0);
            cur = k;
        }
        size_t o = (size_t)n * D_ + lane * 4;
        char4 hx = *(const char4*)(xh + o);
        char4 lx = *(const char4*)(xl + o);
        acc.x += ((int)hx.x << 8) + (int)lx.x;
        acc.y += ((int)hx.y << 8) + (int)lx.y;
        acc.z += ((int)hx.z << 8) + (int)lx.z;
        acc.w += ((int)hx.w << 8) + (int)lx.w;
    }
    {
        bool full = (offsets[cur] >= wbase) && (offsets[cur + 1] <= wbase + 64);
        float* dwk = dw + (size_t)cur * D_ + lane * 4;
        if (full) {
            ((float2*)dwk)[0] = make_float2(sc * acc.x, sc * acc.y);
            ((float2*)dwk)[1] = make_float2(sc * acc.z, sc * acc.w);
        } else {
            atomicAdd(dwk + 0, sc * acc.x);
            atomicAdd(dwk + 1, sc * acc.y);
            atomicAdd(dwk + 2, sc * acc.z);
            atomicAdd(dwk + 3, sc * acc.w);
        }
    }
}

// Quantize + loss (LDS-transposed embedding gather) + folded head-zero.
__global__ __launch_bounds__(256) void k_quant(
    const float* __restrict__ inp, const float* __restrict__ emb,
    const int* __restrict__ idx, float* __restrict__ outp, float* __restrict__ losssum,
    float* __restrict__ enc)
{
    __shared__ float qt[64][260];
    __shared__ int karr[64];
    __shared__ float red[256];
    const int tid = threadIdx.x;
    const int bid = blockIdx.x;        // 1024 blocks: b(64) x hwtile(16)
    const int b = bid >> 4;
    const int ht = bid & 15;
    const int base_n = b * HW_ + ht * 64;

    {
        const float4 z4 = make_float4(0.f, 0.f, 0.f, 0.f);
        float4* pz = (float4*)(enc + 2);
        int t = bid * 256 + tid;       // 262144 threads
        #pragma unroll
        for (int it = 0; it < 9; ++it) {
            int i = it * 262144 + t;
            if (i < ZHEAD_F4) pz[i] = z4;
        }
        if (t == 0) { enc[0] = 0.f; enc[1] = 0.f; enc[67108862] = 0.f; enc[67108863] = 0.f; }
    }

    if (tid < 64) karr[tid] = idx[base_n + tid];
    __syncthreads();

    #pragma unroll
    for (int it = 0; it < 16; ++it) {
        int f = it * 256 + tid;
        int r = f >> 6;
        int c4 = (f & 63) << 2;
        float4 v = ((const float4*)emb)[karr[r] * 64 + (c4 >> 2)];
        *(float4*)(&qt[r][c4]) = v;
    }
    __syncthreads();

    float s = 0.0f;
    #pragma unroll
    for (int it = 0; it < 16; ++it) {
        int f = it * 256 + tid;
        int c = f >> 4;
        int hl = (f & 15) << 2;
        int g = b * 65536 + c * 256 + ht * 16 + (hl >> 2);
        float4 x = ((const float4*)inp)[g];
        float q0 = qt[hl + 0][c];
        float q1 = qt[hl + 1][c];
        float q2 = qt[hl + 2][c];
        float q3 = qt[hl + 3][c];
        float d0 = q0 - x.x, d1 = q1 - x.y, d2 = q2 - x.z, d3 = q3 - x.w;
        ((float4*)outp)[g] = make_float4(x.x + d0, x.y + d1, x.z + d2, x.w + d3);
        s += d0 * d0 + d1 * d1 + d2 * d2 + d3 * d3;
    }
    red[tid] = s;
    __syncthreads();
    for (int t = 128; t > 0; t >>= 1) {
        if (tid < t) red[tid] += red[tid + t];
        __syncthreads();
    }
    if (tid == 0) atomicAdd(losssum, red[0]);
}

// Final fused kernel: cluster EMA, ema_w/new_embedding, loss+entropy, one-hot writes.
__global__ __launch_bounds__(256) void k_fin(
    const float* __restrict__ ema_cs, const int* __restrict__ counts,
    const float* __restrict__ losssum, const float* __restrict__ ema_w,
    const int* __restrict__ idx,
    float* __restrict__ neww, float* __restrict__ newemb,
    float* __restrict__ out_cluster, float* __restrict__ out_loss,
    float* __restrict__ out_ent, float* __restrict__ enc)
{
    __shared__ float sraw[1024];
    __shared__ float red[256];
    __shared__ float sclv;
    const int tid = threadIdx.x;
    const int bid = blockIdx.x;
    float part = 0.f;
    float ent = 0.f;
    #pragma unroll
    for (int j = 0; j < 4; ++j) {
        int k = tid + j * 256;
        float cnt = (float)counts[k];
        float raw = ema_cs[k] * DECAY_ + OMD_ * cnt;
        sraw[k] = raw;
        part += raw;
        float p = cnt * (1.0f / 65536.0f);
        ent += p * logf(p + 1e-10f);
    }
    red[tid] = part;
    __syncthreads();
    for (int t = 128; t > 0; t >>= 1) {
        if (tid < t) red[tid] += red[tid + t];
        __syncthreads();
    }
    float nsum = red[0];
    __syncthreads();
    red[tid] = ent;
    __syncthreads();
    for (int t = 128; t > 0; t >>= 1) {
        if (tid < t) red[tid] += red[tid + t];
        __syncthreads();
    }
    if (tid == 0) {
        float clv = (sraw[bid] + EPS_) / (nsum + 1024.0f * EPS_) * nsum;
        sclv = clv;
        out_cluster[bid] = clv;
        if (bid == 0) {
            out_ent[0] = -red[0];
            out_loss[0] = 0.25f * losssum[0] * (1.0f / 16777216.0f);
        }
    }
    __syncthreads();
    float clv = sclv;
    int g = bid * 256 + tid;
    float w = ema_w[g] * DECAY_ + OMD_ * neww[g];
    neww[g] = w;
    newemb[g] = w / clv;
    if (tid < 64) {
        int n = bid * 64 + tid;
        enc[(size_t)n * 1024 + idx[n]] = 1.0f;
    }
}

extern "C" void kernel_launch(void* const* d_in, const int* in_sizes, int n_in,
                              void* d_out, int out_size, void* d_ws, size_t ws_size,
                              hipStream_t stream)
{
    const float* inp    = (const float*)d_in[0];
    const float* emb    = (const float*)d_in[1];
    const float* ema_cs = (const float*)d_in[2];
    const float* ema_w  = (const float*)d_in[3];

    float* out0        = (float*)d_out;
    float* out_loss    = out0 + OFF_LOSS;
    float* out_ent     = out0 + OFF_ENT;
    float* out_enc     = out0 + OFF_ENC;
    float* out_cluster = out0 + OFF_CLUSTER;
    float* out_neww    = out0 + OFF_NEWW;
    float* out_newemb  = out0 + OFF_NEWEMB;

    signed char* ws_xh = (signed char*)(out0 + OFF_XH);
    signed char* ws_xl = (signed char*)(out0 + OFF_XL);
    signed char* ws_eh = (signed char*)(out0 + OFF_EH);
    signed char* ws_el = (signed char*)(out0 + OFF_EL);
    int*   ws_sorted  = (int*)(out0 + OFF_SORT2);
    int*   ws_offsets = ws_sorted + 65536;
    int*   ws_cursor  = ws_offsets + 1025;

    int*   ws_idx    = (int*)d_ws;
    int*   ws_counts = ws_idx + 65536;
    int*   ws_flagc  = ws_idx + 66560;
    float* ws_loss   = (float*)(ws_idx + 66561);
    int*   ws_flagl  = ws_idx + 66562;
    float* ws_enorm  = (float*)(ws_idx + 132098);

    float4* encz = (float4*)(out0 + ZTAIL_ABS);

    k_prep_e <<<1024, 64, 0, stream>>>(emb, ws_eh, ws_el, ws_enorm);
    k_prep_x <<<2048, 256, 0, stream>>>(inp, ws_xh, ws_xl, out_neww, ws_counts, ws_cursor);
    k_argmin <<<512, 256, 0, stream>>>(ws_xh, ws_xl, ws_eh, ws_el, ws_enorm,
                                       ws_idx, ws_flagc, ws_flagl, encz, ws_counts);
    k_rescan <<<256, 256, 0, stream>>>(inp, emb, ws_flagc, ws_flagl, ws_idx, ws_counts);
    k_scatter<<<64, 256, 0, stream>>>(ws_idx, ws_counts, ws_cursor, ws_sorted, ws_offsets);
    k_dwg    <<<256, 256, 0, stream>>>(ws_xh, ws_xl, ws_sorted, ws_idx, ws_offsets, out_neww);
    k_quant  <<<1024, 256, 0, stream>>>(inp, emb, ws_idx, out0, ws_loss, out_enc);
    k_fin    <<<1024, 256, 0, stream>>>(ema_cs, ws_counts, ws_loss, ema_w, ws_idx,
                                        out_neww, out_newemb, out_cluster, out_loss,
                                        out_ent, out_enc);
}